// Round 14
// baseline (626.082 us; speedup 1.0000x reference)
//
#include <hip/hip_runtime.h>
#include <hip/hip_fp16.h>
#include <math.h>

// N=100000, E=1600000, G=64, H=4, C=64, NODE_F=32, DRONE_F=16, OUT=32, L=2

#define NEG_SLOPE 0.2f
#define LN_EPS 1e-5f

struct __align__(8) h16x4 { __half x, y, z, w; };

// cnt=0 + layer-0 weight prep (wt0 transpose, uv0). Replaces the memset slot.
__global__ __launch_bounds__(256) void k_init(
        const float* __restrict__ cW0, const float* __restrict__ s0,
        const float* __restrict__ d0, float* __restrict__ wt0,
        float* __restrict__ uv, int* __restrict__ cnt, int N) {
    int i = blockIdx.x * 256 + threadIdx.x;
    if (i < N) cnt[i] = 0;
    if (i < 16384) { int co = i >> 6, k = i & 63; wt0[k * 256 + co] = cW0[i]; }
    if (i < 512) {
        int sd = (i >> 8) & 1, head = (i >> 6) & 3, kk = i & 63;
        const float* att = sd ? d0 : s0;
        float acc = 0.f;
        for (int c = 0; c < 64; ++c)
            acc += cW0[(head * 64 + c) * 64 + kk] * att[head * 64 + c];
        uv[i] = acc;
    }
}

#define XPAD 68

// xh layer-0 block body (h0 fused). LDS-DIET version: h0 result goes to
// registers first; hs[32][68] is then ALIASED over the dead wn/wd region
// (weights no longer needed) -> 19136 B total instead of 28160 B.
__device__ __forceinline__ void xh0_block(
        int n0, const float* __restrict__ wt, const float* __restrict__ uv_l,
        __half* __restrict__ xh, float* __restrict__ as_, float* __restrict__ ad_,
        const float* __restrict__ x, const int* __restrict__ batch,
        const float* __restrict__ node_W, const float* __restrict__ drone_W,
        const float* __restrict__ node_b, const float* __restrict__ drone_b,
        const float* __restrict__ drone_feat, float* __restrict__ h_out, int N,
        float* smem_f) {
    // layout (floats): wn[32][65] @0 (2080) | wd[16][65] @2080 (1040) |
    //                  bs @3120 (64) | xs[32][33] @3184 (1056) | ds[32][17] @4240 (544)
    // hs[32][68] (2176 floats) aliases @0 (over wn+wd, dead after h0 phase)
    float (*wn)[65] = (float(*)[65])smem_f;
    float (*wd)[65] = (float(*)[65])(smem_f + 2080);
    float* bs = smem_f + 3120;
    float (*xs)[33] = (float(*)[33])(smem_f + 3184);
    float (*ds)[17] = (float(*)[17])(smem_f + 4240);
    float (*hs)[XPAD] = (float(*)[XPAD])smem_f;
    int t = threadIdx.x;
    for (int i = t; i < 2048; i += 256) { int co = i >> 5, k = i & 31; wn[k][co] = node_W[i]; }
    for (int i = t; i < 1024; i += 256) { int co = i >> 4, k = i & 15; wd[k][co] = drone_W[i]; }
    if (t < 64) bs[t] = node_b[t] + drone_b[t];
    for (int i = t; i < 1024; i += 256) {
        int r = i >> 5, c = i & 31;
        int n = n0 + r;
        xs[r][c] = (n < N) ? x[(size_t)n * 32 + c] : 0.f;
    }
    for (int i = t; i < 512; i += 256) {
        int r = i >> 4, c = i & 15;
        int n = n0 + r;
        int g = (n < N) ? batch[n] : 0;
        ds[r][c] = drone_feat[g * 16 + c];
    }
    __syncthreads();
    int co = t & 63, nsub = t >> 6;
    float a[8];
    {
        float b = bs[co];
#pragma unroll
        for (int j = 0; j < 8; ++j) {
            int r = nsub * 8 + j;
            float acc = b;
#pragma unroll
            for (int k = 0; k < 32; ++k) acc = fmaf(xs[r][k], wn[k][co], acc);
#pragma unroll
            for (int k = 0; k < 16; ++k) acc = fmaf(ds[r][k], wd[k][co], acc);
            a[j] = acc;
        }
    }
    __syncthreads();   // all reads of wn/wd/xs/ds done -> safe to overlay hs
#pragma unroll
    for (int j = 0; j < 8; ++j) {
        int r = nsub * 8 + j;
        hs[r][co] = a[j];
        int n = n0 + r;
        if (n < N) h_out[(size_t)n * 64 + co] = a[j];
    }
    __syncthreads();
    int co4 = (t & 63) * 4;
    float4 acc[8];
#pragma unroll
    for (int j = 0; j < 8; ++j) acc[j] = make_float4(0.f, 0.f, 0.f, 0.f);
    const float* wp = wt + co4;
#pragma unroll 2
    for (int k4 = 0; k4 < 16; ++k4) {
        float4 w0 = *(const float4*)(wp + (k4 * 4 + 0) * 256);
        float4 w1 = *(const float4*)(wp + (k4 * 4 + 1) * 256);
        float4 w2 = *(const float4*)(wp + (k4 * 4 + 2) * 256);
        float4 w3 = *(const float4*)(wp + (k4 * 4 + 3) * 256);
#pragma unroll
        for (int j = 0; j < 8; ++j) {
            float4 hv = *(const float4*)&hs[nsub * 8 + j][k4 * 4];
            float4 v = acc[j];
            v.x = fmaf(hv.x, w0.x, fmaf(hv.y, w1.x, fmaf(hv.z, w2.x, fmaf(hv.w, w3.x, v.x))));
            v.y = fmaf(hv.x, w0.y, fmaf(hv.y, w1.y, fmaf(hv.z, w2.y, fmaf(hv.w, w3.y, v.y))));
            v.z = fmaf(hv.x, w0.z, fmaf(hv.y, w1.z, fmaf(hv.z, w2.z, fmaf(hv.w, w3.z, v.z))));
            v.w = fmaf(hv.x, w0.w, fmaf(hv.y, w1.w, fmaf(hv.z, w2.w, fmaf(hv.w, w3.w, v.w))));
            acc[j] = v;
        }
    }
#pragma unroll
    for (int j = 0; j < 8; ++j) {
        int n = n0 + nsub * 8 + j;
        if (n < N) {
            h16x4 o;
            o.x = __float2half(acc[j].x);
            o.y = __float2half(acc[j].y);
            o.z = __float2half(acc[j].z);
            o.w = __float2half(acc[j].w);
            *(h16x4*)(xh + (size_t)n * 256 + co4) = o;
        }
    }
    {
        int row  = t >> 3;
        int head = (t >> 1) & 3;
        int sd   = t & 1;
        int n = n0 + row;
        if (n < N) {
            const float* u = uv_l + sd * 256 + head * 64;
            float av = 0.f;
#pragma unroll
            for (int k4 = 0; k4 < 16; ++k4) {
                float4 hv = *(const float4*)&hs[row][k4 * 4];
                float4 uu = *(const float4*)(u + k4 * 4);
                av += hv.x * uu.x + hv.y * uu.y + hv.z * uu.z + hv.w * uu.w;
            }
            (sd ? ad_ : as_)[n * 4 + head] = av;
        }
    }
}

// Merged: scatter-role blocks [0, NS*8) do the 8-pass windowed edge scatter
// (+ wt1/owT/uv1 prep on blocks 0..127); xh-role blocks run layer-0 xh.
__global__ __launch_bounds__(256) void k_sx(
        const int* __restrict__ edge_index, int* __restrict__ cnt,
        int* __restrict__ csrB,
        const float* __restrict__ cW1, const float* __restrict__ s1,
        const float* __restrict__ d1, const float* __restrict__ out_W,
        float* __restrict__ wt1, float* __restrict__ uv, float* __restrict__ owT,
        int E, int S, int NS,
        const float* __restrict__ wt0, __half* __restrict__ xh,
        float* __restrict__ as_, float* __restrict__ ad_,
        const float* __restrict__ x, const int* __restrict__ batch,
        const float* __restrict__ node_W, const float* __restrict__ drone_W,
        const float* __restrict__ node_b, const float* __restrict__ drone_b,
        const float* __restrict__ drone_feat, float* __restrict__ h_out, int N) {
    __shared__ float smem_f[4784];   // 19136 B -> 8 blocks/CU
    int bid = blockIdx.x;
    int SCAT = NS * 8;
    if (bid < SCAT) {
        if (bid < 128) {
            int i = bid * 256 + threadIdx.x;   // 0..32767
            if (i < 16384) { int co = i >> 6, k = i & 63; wt1[k * 256 + co] = cW1[i]; }
            if (i < 2048) { int k = i >> 5, o = i & 31; owT[i] = out_W[o * 64 + k]; }
            if (i < 512) {
                int sd = (i >> 8) & 1, head = (i >> 6) & 3, kk = i & 63;
                const float* att = sd ? d1 : s1;
                float acc = 0.f;
                for (int c = 0; c < 64; ++c)
                    acc += cW1[(head * 64 + c) * 64 + kk] * att[head * 64 + c];
                uv[512 + i] = acc;
            }
        }
        int pass = bid / NS, bx = bid - pass * NS;
        int lo = pass * S, hi = lo + S;
        int i = (bx * 256 + threadIdx.x) * 4;
        if (i + 3 < E) {
            int4 sv = *(const int4*)(edge_index + i);
            int4 dv = *(const int4*)(edge_index + E + i);
            int sl;
            if (dv.x >= lo && dv.x < hi) { sl = atomicAdd(cnt + dv.x, 1); if (sl < 63) csrB[((size_t)dv.x << 6) + 1 + sl] = sv.x; }
            if (dv.y >= lo && dv.y < hi) { sl = atomicAdd(cnt + dv.y, 1); if (sl < 63) csrB[((size_t)dv.y << 6) + 1 + sl] = sv.y; }
            if (dv.z >= lo && dv.z < hi) { sl = atomicAdd(cnt + dv.z, 1); if (sl < 63) csrB[((size_t)dv.z << 6) + 1 + sl] = sv.z; }
            if (dv.w >= lo && dv.w < hi) { sl = atomicAdd(cnt + dv.w, 1); if (sl < 63) csrB[((size_t)dv.w << 6) + 1 + sl] = sv.w; }
        } else {
            for (int k = i; k < E; ++k) {
                int d = edge_index[E + k];
                if (d >= lo && d < hi) {
                    int sl = atomicAdd(cnt + d, 1);
                    if (sl < 63) csrB[((size_t)d << 6) + 1 + sl] = edge_index[k];
                }
            }
        }
    } else {
        int n0 = (bid - SCAT) * 32;
        xh0_block(n0, wt0, uv, xh, as_, ad_, x, batch, node_W, drone_W,
                  node_b, drone_b, drone_feat, h_out, N, smem_f);
    }
}

// xh (layer 1): reads h from global. Unchanged.
__global__ __launch_bounds__(256) void k_xh1(
        const float* __restrict__ h, const float* __restrict__ wt,
        const float* __restrict__ uv_l, __half* __restrict__ xh,
        float* __restrict__ as_, float* __restrict__ ad_, int N) {
    __shared__ float hs[32][XPAD];
    int t = threadIdx.x;
    int n0 = blockIdx.x * 32;
    for (int i = t; i < 32 * 64; i += 256) {
        int r = i >> 6, c = i & 63;
        int n = n0 + r;
        hs[r][c] = (n < N) ? h[(size_t)n * 64 + c] : 0.f;
    }
    __syncthreads();
    int co4 = (t & 63) * 4;
    int nsub = t >> 6;
    float4 acc[8];
#pragma unroll
    for (int j = 0; j < 8; ++j) acc[j] = make_float4(0.f, 0.f, 0.f, 0.f);
    const float* wp = wt + co4;
#pragma unroll 2
    for (int k4 = 0; k4 < 16; ++k4) {
        float4 w0 = *(const float4*)(wp + (k4 * 4 + 0) * 256);
        float4 w1 = *(const float4*)(wp + (k4 * 4 + 1) * 256);
        float4 w2 = *(const float4*)(wp + (k4 * 4 + 2) * 256);
        float4 w3 = *(const float4*)(wp + (k4 * 4 + 3) * 256);
#pragma unroll
        for (int j = 0; j < 8; ++j) {
            float4 hv = *(const float4*)&hs[nsub * 8 + j][k4 * 4];
            float4 a = acc[j];
            a.x = fmaf(hv.x, w0.x, fmaf(hv.y, w1.x, fmaf(hv.z, w2.x, fmaf(hv.w, w3.x, a.x))));
            a.y = fmaf(hv.x, w0.y, fmaf(hv.y, w1.y, fmaf(hv.z, w2.y, fmaf(hv.w, w3.y, a.y))));
            a.z = fmaf(hv.x, w0.z, fmaf(hv.y, w1.z, fmaf(hv.z, w2.z, fmaf(hv.w, w3.z, a.z))));
            a.w = fmaf(hv.x, w0.w, fmaf(hv.y, w1.w, fmaf(hv.z, w2.w, fmaf(hv.w, w3.w, a.w))));
            acc[j] = a;
        }
    }
#pragma unroll
    for (int j = 0; j < 8; ++j) {
        int n = n0 + nsub * 8 + j;
        if (n < N) {
            h16x4 o;
            o.x = __float2half(acc[j].x);
            o.y = __float2half(acc[j].y);
            o.z = __float2half(acc[j].z);
            o.w = __float2half(acc[j].w);
            *(h16x4*)(xh + (size_t)n * 256 + co4) = o;
        }
    }
    {
        int row  = t >> 3;
        int head = (t >> 1) & 3;
        int sd   = t & 1;
        int n = n0 + row;
        if (n < N) {
            const float* u = uv_l + sd * 256 + head * 64;
            float a = 0.f;
#pragma unroll
            for (int k4 = 0; k4 < 16; ++k4) {
                float4 hv = *(const float4*)&hs[row][k4 * 4];
                float4 uu = *(const float4*)(u + k4 * 4);
                a += hv.x * uu.x + hv.y * uu.y + hv.z * uu.z + hv.w * uu.w;
            }
            (sd ? ad_ : as_)[n * 4 + head] = a;
        }
    }
}

__device__ __forceinline__ __half2 shxor_h2(__half2 a, int m) {
    int u = __shfl_xor(*(int*)&a, m, 64);
    return *(__half2*)&u;
}

// One wave per dst node; 16 lanes/edge; 3-stage pipeline x2 (8 edges/trip).
// Implicit self-loop in slot 0. 32-bit byte-offset addressing.
// LAST: output projection via LDS-staged owT/hout. (Unchanged.)
template <bool LAST>
__global__ __launch_bounds__(256) void k_gat(
        const __half* __restrict__ xh, const float* __restrict__ as_,
        const float* __restrict__ ad_, const int* __restrict__ cnt,
        const int* __restrict__ csrB, const float* __restrict__ convb,
        const float* __restrict__ ln_g, const float* __restrict__ ln_b,
        float* __restrict__ h, const float* __restrict__ owT,
        const float* __restrict__ out_b, float* __restrict__ out, int N) {
    __shared__ float owT_lds[2048];
    __shared__ float hout_lds4[4][64];
    int t = threadIdx.x;
    int wid = t >> 6, lane = t & 63;
    if (LAST) {
        for (int i = t; i < 2048; i += 256) owT_lds[i] = owT[i];
        __syncthreads();
    }
    int n = blockIdx.x * 4 + wid;
    if (n >= N) return;
    float* hout_lds = hout_lds4[wid];
    int g    = lane >> 4;
    int l16  = lane & 15;
    int head = l16 >> 2;
    int r0 = n << 6;
    int r1 = r0 + 1 + min(cnt[n], 63);
    float adv = ad_[(size_t)n * 4 + head];
    const char* xbb = (const char*)xh + (l16 << 5);
    const char* asb = (const char*)as_ + (head << 2);
    const char* cbb = (const char*)csrB;

    float s = 0.f;
    __half2 acc[8];
#pragma unroll
    for (int j = 0; j < 8; ++j) acc[j] = __float2half2_rn(0.f);

    uint4 zero4 = make_uint4(0u, 0u, 0u, 0u);
    int idx;
    idx = r0 + g;      bool vA = idx < r1; int sA = n; if (g != 0 && vA) sA = *(const int*)(cbb + ((unsigned)idx << 2));
    idx = r0 + 4 + g;  bool vB = idx < r1; int sB = 0; if (vB) sB = *(const int*)(cbb + ((unsigned)idx << 2));
    idx = r0 + 8 + g;  bool vC = idx < r1; int sC = 0; if (vC) sC = *(const int*)(cbb + ((unsigned)idx << 2));
    idx = r0 + 12 + g; bool vD = idx < r1; int sD = 0; if (vD) sD = *(const int*)(cbb + ((unsigned)idx << 2));
    float asA = 0.f, asB = 0.f;
    uint4 qA0 = zero4, qA1 = zero4, qB0 = zero4, qB1 = zero4;
    if (vA) {
        asA = *(const float*)(asb + ((unsigned)sA << 4));
        const uint4* bp = (const uint4*)(xbb + ((unsigned)sA << 9));
        qA0 = bp[0]; qA1 = bp[1];
    }
    if (vB) {
        asB = *(const float*)(asb + ((unsigned)sB << 4));
        const uint4* bp = (const uint4*)(xbb + ((unsigned)sB << 9));
        qB0 = bp[0]; qB1 = bp[1];
    }

    auto COMPUTE = [&](bool vc, float asc, const uint4& q0, const uint4& q1) {
        float e = asc + adv;
        e = e > 0.f ? e : NEG_SLOPE * e;
        float w = __expf(e);
        w = vc ? w : 0.f;
        s += w;
        __half2 w2 = __float2half2_rn(w);
        const __half2* ha = (const __half2*)&q0;
        const __half2* hb = (const __half2*)&q1;
        acc[0] = __hfma2(w2, ha[0], acc[0]);
        acc[1] = __hfma2(w2, ha[1], acc[1]);
        acc[2] = __hfma2(w2, ha[2], acc[2]);
        acc[3] = __hfma2(w2, ha[3], acc[3]);
        acc[4] = __hfma2(w2, hb[0], acc[4]);
        acc[5] = __hfma2(w2, hb[1], acc[5]);
        acc[6] = __hfma2(w2, hb[2], acc[6]);
        acc[7] = __hfma2(w2, hb[3], acc[7]);
    };

    for (int i = r0; i < r1; i += 8) {
        COMPUTE(vA, asA, qA0, qA1);
        int idxE = i + 16 + g; bool vE = idxE < r1; int sE = 0;
        if (vE) sE = *(const int*)(cbb + ((unsigned)idxE << 2));
        vA = vC;
        if (vC) {
            asA = *(const float*)(asb + ((unsigned)sC << 4));
            const uint4* bp = (const uint4*)(xbb + ((unsigned)sC << 9));
            qA0 = bp[0]; qA1 = bp[1];
        }
        COMPUTE(vB, asB, qB0, qB1);
        int idxF = i + 20 + g; bool vF = idxF < r1; int sF = 0;
        if (vF) sF = *(const int*)(cbb + ((unsigned)idxF << 2));
        vB = vD;
        if (vD) {
            asB = *(const float*)(asb + ((unsigned)sD << 4));
            const uint4* bp = (const uint4*)(xbb + ((unsigned)sD << 9));
            qB0 = bp[0]; qB1 = bp[1];
        }
        vC = vE; sC = sE;
        vD = vF; sD = sF;
    }

    s += __shfl_xor(s, 16, 64);
    s += __shfl_xor(s, 32, 64);
#pragma unroll
    for (int j = 0; j < 8; ++j) {
        acc[j] = __hadd2(acc[j], shxor_h2(acc[j], 16));
        acc[j] = __hadd2(acc[j], shxor_h2(acc[j], 32));
    }
    float inv = 1.f / (s + 1e-16f);
    __half2 ih = __float2half2_rn(inv);
#pragma unroll
    for (int j = 0; j < 8; ++j) {
        acc[j] = __hmul2(acc[j], ih);
        acc[j] = __hadd2(acc[j], shxor_h2(acc[j], 4));
        acc[j] = __hadd2(acc[j], shxor_h2(acc[j], 8));
    }
    float f[16];
#pragma unroll
    for (int j = 0; j < 8; ++j) {
        float2 tv = __half22float2(acc[j]);
        f[2 * j]     = tv.x;
        f[2 * j + 1] = tv.y;
    }
    int cblk = lane & 3;
    int cb16 = cblk * 16;
    float o[16];
    float part = 0.f;
#pragma unroll
    for (int q = 0; q < 4; ++q) {
        float4 cb = *(const float4*)(convb + cb16 + q * 4);
        o[q * 4 + 0] = 0.25f * f[q * 4 + 0] + cb.x;
        o[q * 4 + 1] = 0.25f * f[q * 4 + 1] + cb.y;
        o[q * 4 + 2] = 0.25f * f[q * 4 + 2] + cb.z;
        o[q * 4 + 3] = 0.25f * f[q * 4 + 3] + cb.w;
        part += o[q * 4 + 0] + o[q * 4 + 1] + o[q * 4 + 2] + o[q * 4 + 3];
    }
    part += __shfl_xor(part, 1, 64);
    part += __shfl_xor(part, 2, 64);
    float mu = part * (1.f / 64.f);
    float vs = 0.f;
#pragma unroll
    for (int j = 0; j < 16; ++j) { o[j] -= mu; vs += o[j] * o[j]; }
    vs += __shfl_xor(vs, 1, 64);
    vs += __shfl_xor(vs, 2, 64);
    float rstd = rsqrtf(vs * (1.f / 64.f) + LN_EPS);

    if (!LAST) {
        if (lane < 4) {
            float4* hp = (float4*)(h + (size_t)n * 64 + cb16);
#pragma unroll
            for (int q = 0; q < 4; ++q) {
                float4 hv = hp[q];
                float4 gv = *(const float4*)(ln_g + cb16 + q * 4);
                float4 bv = *(const float4*)(ln_b + cb16 + q * 4);
                hv.x += fmaxf(o[q * 4 + 0] * rstd * gv.x + bv.x, 0.f);
                hv.y += fmaxf(o[q * 4 + 1] * rstd * gv.y + bv.y, 0.f);
                hv.z += fmaxf(o[q * 4 + 2] * rstd * gv.z + bv.z, 0.f);
                hv.w += fmaxf(o[q * 4 + 3] * rstd * gv.w + bv.w, 0.f);
                hp[q] = hv;
            }
        }
    } else {
        if (lane < 4) {
            const float4* hp = (const float4*)(h + (size_t)n * 64 + cb16);
#pragma unroll
            for (int q = 0; q < 4; ++q) {
                float4 hv = hp[q];
                float4 gv = *(const float4*)(ln_g + cb16 + q * 4);
                float4 bv = *(const float4*)(ln_b + cb16 + q * 4);
                hout_lds[cb16 + q * 4 + 0] = hv.x + fmaxf(o[q * 4 + 0] * rstd * gv.x + bv.x, 0.f);
                hout_lds[cb16 + q * 4 + 1] = hv.y + fmaxf(o[q * 4 + 1] * rstd * gv.y + bv.y, 0.f);
                hout_lds[cb16 + q * 4 + 2] = hv.z + fmaxf(o[q * 4 + 2] * rstd * gv.z + bv.z, 0.f);
                hout_lds[cb16 + q * 4 + 3] = hv.w + fmaxf(o[q * 4 + 3] * rstd * gv.w + bv.w, 0.f);
            }
        }
        asm volatile("s_waitcnt lgkmcnt(0)" ::: "memory");
        if (lane < 32) {
            float acc2 = out_b[lane];
#pragma unroll 8
            for (int k = 0; k < 64; ++k)
                acc2 = fmaf(hout_lds[k], owT_lds[k * 32 + lane], acc2);
            out[(size_t)n * 32 + lane] = acc2;
        }
    }
}

static inline unsigned cdiv(long long a, long long b) { return (unsigned)((a + b - 1) / b); }

extern "C" void kernel_launch(void* const* d_in, const int* in_sizes, int n_in,
                              void* d_out, int out_size, void* d_ws, size_t ws_size,
                              hipStream_t stream) {
    const float* x          = (const float*)d_in[0];
    const float* drone_feat = (const float*)d_in[1];
    const int*   edge_index = (const int*)d_in[2];
    const int*   batch      = (const int*)d_in[3];
    const float* node_W     = (const float*)d_in[4];
    const float* node_b     = (const float*)d_in[5];
    const float* drone_W    = (const float*)d_in[6];
    const float* drone_b    = (const float*)d_in[7];
    const float* convW[2]   = {(const float*)d_in[8],  (const float*)d_in[14]};
    const float* att_src[2] = {(const float*)d_in[9],  (const float*)d_in[15]};
    const float* att_dst[2] = {(const float*)d_in[10], (const float*)d_in[16]};
    const float* convb[2]   = {(const float*)d_in[11], (const float*)d_in[17]};
    const float* ln_g[2]    = {(const float*)d_in[12], (const float*)d_in[18]};
    const float* ln_b[2]    = {(const float*)d_in[13], (const float*)d_in[19]};
    const float* out_W      = (const float*)d_in[20];
    const float* out_b      = (const float*)d_in[21];
    float* out = (float*)d_out;

    const int N = in_sizes[0] / 32;
    const int E = in_sizes[2] / 2;
    const int P = 8;                        // scatter passes
    const int S = cdiv(N, P);               // dst range per pass
    const int NS = cdiv(cdiv(E, 4), 256);   // scatter blocks per pass

    char* base = (char*)d_ws;
    size_t off = 0;
    auto alloc = [&](size_t bytes) {
        char* p = base + off;
        off = (off + bytes + 255) & ~(size_t)255;
        return p;
    };
    float*           h      = (float*)alloc((size_t)N * 64 * 4);
    __half*          xh     = (__half*)alloc((size_t)N * 256 * 2);
    float*           as_    = (float*)alloc((size_t)N * 4 * 4);
    float*           ad_    = (float*)alloc((size_t)N * 4 * 4);
    float*           wt0    = (float*)alloc((size_t)256 * 64 * 4);
    float*           wt1    = (float*)alloc((size_t)256 * 64 * 4);
    float*           uv     = (float*)alloc((size_t)1024 * 4);
    float*           owT    = (float*)alloc((size_t)2048 * 4);
    int*             cnt    = (int*)alloc((size_t)N * 4);
    int*             csrB   = (int*)alloc((size_t)N * 64 * 4);
    (void)ws_size;

    // D1: cnt=0 + layer-0 weight prep (wt0, uv0)
    k_init<<<cdiv(N, 256), 256, 0, stream>>>(convW[0], att_src[0], att_dst[0],
                                             wt0, uv, cnt, N);
    // D2: merged {8-pass windowed scatter + wt1/owT/uv1 prep} || {layer-0 xh (h0 fused)}
    k_sx<<<NS * P + cdiv(N, 32), 256, 0, stream>>>(
        edge_index, cnt, csrB,
        convW[1], att_src[1], att_dst[1], out_W,
        wt1, uv, owT, E, S, NS,
        wt0, xh, as_, ad_,
        x, batch, node_W, drone_W, node_b, drone_b, drone_feat, h, N);
    // D3-D5: gat0, xh1, gat1 (final gat fuses the output projection)
    k_gat<false><<<cdiv(N, 4), 256, 0, stream>>>(xh, as_, ad_, cnt, csrB, convb[0],
                                                 ln_g[0], ln_b[0], h, owT, out_b, out, N);
    k_xh1<<<cdiv(N, 32), 256, 0, stream>>>(h, wt1, uv + 512, xh, as_, ad_, N);
    k_gat<true><<<cdiv(N, 4), 256, 0, stream>>>(xh, as_, ad_, cnt, csrB, convb[1],
                                                ln_g[1], ln_b[1], h, owT, out_b, out, N);
}

// Round 15
// 615.903 us; speedup vs baseline: 1.0165x; 1.0165x over previous
//
#include <hip/hip_runtime.h>
#include <hip/hip_fp16.h>
#include <math.h>

// N=100000, E=1600000, G=64, H=4, C=64, NODE_F=32, DRONE_F=16, OUT=32, L=2

#define NEG_SLOPE 0.2f
#define LN_EPS 1e-5f

struct __align__(8) h16x4 { __half x, y, z, w; };

// cnt=0 + layer-0 weight prep (wt0 transpose, uv0). Replaces the memset slot.
__global__ __launch_bounds__(256) void k_init(
        const float* __restrict__ cW0, const float* __restrict__ s0,
        const float* __restrict__ d0, float* __restrict__ wt0,
        float* __restrict__ uv, int* __restrict__ cnt, int N) {
    int i = blockIdx.x * 256 + threadIdx.x;
    if (i < N) cnt[i] = 0;
    if (i < 16384) { int co = i >> 6, k = i & 63; wt0[k * 256 + co] = cW0[i]; }
    if (i < 512) {
        int sd = (i >> 8) & 1, head = (i >> 6) & 3, kk = i & 63;
        const float* att = sd ? d0 : s0;
        float acc = 0.f;
        for (int c = 0; c < 64; ++c)
            acc += cW0[(head * 64 + c) * 64 + kk] * att[head * 64 + c];
        uv[i] = acc;
    }
}

#define XPAD 68

// xh layer-0 block body (h0 fused). LDS-diet: h0 result to registers,
// hs[32][68] aliased over the dead wn/wd region -> 19136 B total.
__device__ __forceinline__ void xh0_block(
        int n0, const float* __restrict__ wt, const float* __restrict__ uv_l,
        __half* __restrict__ xh, float* __restrict__ as_, float* __restrict__ ad_,
        const float* __restrict__ x, const int* __restrict__ batch,
        const float* __restrict__ node_W, const float* __restrict__ drone_W,
        const float* __restrict__ node_b, const float* __restrict__ drone_b,
        const float* __restrict__ drone_feat, float* __restrict__ h_out, int N,
        float* smem_f) {
    float (*wn)[65] = (float(*)[65])smem_f;
    float (*wd)[65] = (float(*)[65])(smem_f + 2080);
    float* bs = smem_f + 3120;
    float (*xs)[33] = (float(*)[33])(smem_f + 3184);
    float (*ds)[17] = (float(*)[17])(smem_f + 4240);
    float (*hs)[XPAD] = (float(*)[XPAD])smem_f;
    int t = threadIdx.x;
    for (int i = t; i < 2048; i += 256) { int co = i >> 5, k = i & 31; wn[k][co] = node_W[i]; }
    for (int i = t; i < 1024; i += 256) { int co = i >> 4, k = i & 15; wd[k][co] = drone_W[i]; }
    if (t < 64) bs[t] = node_b[t] + drone_b[t];
    for (int i = t; i < 1024; i += 256) {
        int r = i >> 5, c = i & 31;
        int n = n0 + r;
        xs[r][c] = (n < N) ? x[(size_t)n * 32 + c] : 0.f;
    }
    for (int i = t; i < 512; i += 256) {
        int r = i >> 4, c = i & 15;
        int n = n0 + r;
        int g = (n < N) ? batch[n] : 0;
        ds[r][c] = drone_feat[g * 16 + c];
    }
    __syncthreads();
    int co = t & 63, nsub = t >> 6;
    float a[8];
    {
        float b = bs[co];
#pragma unroll
        for (int j = 0; j < 8; ++j) {
            int r = nsub * 8 + j;
            float acc = b;
#pragma unroll
            for (int k = 0; k < 32; ++k) acc = fmaf(xs[r][k], wn[k][co], acc);
#pragma unroll
            for (int k = 0; k < 16; ++k) acc = fmaf(ds[r][k], wd[k][co], acc);
            a[j] = acc;
        }
    }
    __syncthreads();   // all reads of wn/wd/xs/ds done -> safe to overlay hs
#pragma unroll
    for (int j = 0; j < 8; ++j) {
        int r = nsub * 8 + j;
        hs[r][co] = a[j];
        int n = n0 + r;
        if (n < N) h_out[(size_t)n * 64 + co] = a[j];
    }
    __syncthreads();
    int co4 = (t & 63) * 4;
    float4 acc[8];
#pragma unroll
    for (int j = 0; j < 8; ++j) acc[j] = make_float4(0.f, 0.f, 0.f, 0.f);
    const float* wp = wt + co4;
#pragma unroll 2
    for (int k4 = 0; k4 < 16; ++k4) {
        float4 w0 = *(const float4*)(wp + (k4 * 4 + 0) * 256);
        float4 w1 = *(const float4*)(wp + (k4 * 4 + 1) * 256);
        float4 w2 = *(const float4*)(wp + (k4 * 4 + 2) * 256);
        float4 w3 = *(const float4*)(wp + (k4 * 4 + 3) * 256);
#pragma unroll
        for (int j = 0; j < 8; ++j) {
            float4 hv = *(const float4*)&hs[nsub * 8 + j][k4 * 4];
            float4 v = acc[j];
            v.x = fmaf(hv.x, w0.x, fmaf(hv.y, w1.x, fmaf(hv.z, w2.x, fmaf(hv.w, w3.x, v.x))));
            v.y = fmaf(hv.x, w0.y, fmaf(hv.y, w1.y, fmaf(hv.z, w2.y, fmaf(hv.w, w3.y, v.y))));
            v.z = fmaf(hv.x, w0.z, fmaf(hv.y, w1.z, fmaf(hv.z, w2.z, fmaf(hv.w, w3.z, v.z))));
            v.w = fmaf(hv.x, w0.w, fmaf(hv.y, w1.w, fmaf(hv.z, w2.w, fmaf(hv.w, w3.w, v.w))));
            acc[j] = v;
        }
    }
#pragma unroll
    for (int j = 0; j < 8; ++j) {
        int n = n0 + nsub * 8 + j;
        if (n < N) {
            h16x4 o;
            o.x = __float2half(acc[j].x);
            o.y = __float2half(acc[j].y);
            o.z = __float2half(acc[j].z);
            o.w = __float2half(acc[j].w);
            *(h16x4*)(xh + (size_t)n * 256 + co4) = o;
        }
    }
    {
        int row  = t >> 3;
        int head = (t >> 1) & 3;
        int sd   = t & 1;
        int n = n0 + row;
        if (n < N) {
            const float* u = uv_l + sd * 256 + head * 64;
            float av = 0.f;
#pragma unroll
            for (int k4 = 0; k4 < 16; ++k4) {
                float4 hv = *(const float4*)&hs[row][k4 * 4];
                float4 uu = *(const float4*)(u + k4 * 4);
                av += hv.x * uu.x + hv.y * uu.y + hv.z * uu.z + hv.w * uu.w;
            }
            (sd ? ad_ : as_)[n * 4 + head] = av;
        }
    }
}

// Merged kernel, role-REORDERED: xh-role blocks FIRST [0, NXH) — ALU-heavy,
// they occupy the CUs while the latency-bound scatter blocks [NXH, NXH+NS*8)
// stream in behind them (r14's tail placement serialized the two phases).
// Scatter pass-ordering preserved within its own range.
__global__ __launch_bounds__(256) void k_sx(
        const int* __restrict__ edge_index, int* __restrict__ cnt,
        int* __restrict__ csrB,
        const float* __restrict__ cW1, const float* __restrict__ s1,
        const float* __restrict__ d1, const float* __restrict__ out_W,
        float* __restrict__ wt1, float* __restrict__ uv, float* __restrict__ owT,
        int E, int S, int NS, int NXH,
        const float* __restrict__ wt0, __half* __restrict__ xh,
        float* __restrict__ as_, float* __restrict__ ad_,
        const float* __restrict__ x, const int* __restrict__ batch,
        const float* __restrict__ node_W, const float* __restrict__ drone_W,
        const float* __restrict__ node_b, const float* __restrict__ drone_b,
        const float* __restrict__ drone_feat, float* __restrict__ h_out, int N) {
    __shared__ float smem_f[4784];   // 19136 B
    int bid = blockIdx.x;
    if (bid < NXH) {
        xh0_block(bid * 32, wt0, uv, xh, as_, ad_, x, batch, node_W, drone_W,
                  node_b, drone_b, drone_feat, h_out, N, smem_f);
        return;
    }
    int sb = bid - NXH;
    if (sb < 128) {
        int i = sb * 256 + threadIdx.x;   // 0..32767
        if (i < 16384) { int co = i >> 6, k = i & 63; wt1[k * 256 + co] = cW1[i]; }
        if (i < 2048) { int k = i >> 5, o = i & 31; owT[i] = out_W[o * 64 + k]; }
        if (i < 512) {
            int sd = (i >> 8) & 1, head = (i >> 6) & 3, kk = i & 63;
            const float* att = sd ? d1 : s1;
            float acc = 0.f;
            for (int c = 0; c < 64; ++c)
                acc += cW1[(head * 64 + c) * 64 + kk] * att[head * 64 + c];
            uv[512 + i] = acc;
        }
    }
    int pass = sb / NS, bx = sb - pass * NS;
    int lo = pass * S, hi = lo + S;
    int i = (bx * 256 + threadIdx.x) * 4;
    if (i + 3 < E) {
        int4 sv = *(const int4*)(edge_index + i);
        int4 dv = *(const int4*)(edge_index + E + i);
        int sl;
        if (dv.x >= lo && dv.x < hi) { sl = atomicAdd(cnt + dv.x, 1); if (sl < 63) csrB[((size_t)dv.x << 6) + 1 + sl] = sv.x; }
        if (dv.y >= lo && dv.y < hi) { sl = atomicAdd(cnt + dv.y, 1); if (sl < 63) csrB[((size_t)dv.y << 6) + 1 + sl] = sv.y; }
        if (dv.z >= lo && dv.z < hi) { sl = atomicAdd(cnt + dv.z, 1); if (sl < 63) csrB[((size_t)dv.z << 6) + 1 + sl] = sv.z; }
        if (dv.w >= lo && dv.w < hi) { sl = atomicAdd(cnt + dv.w, 1); if (sl < 63) csrB[((size_t)dv.w << 6) + 1 + sl] = sv.w; }
    } else {
        for (int k = i; k < E; ++k) {
            int d = edge_index[E + k];
            if (d >= lo && d < hi) {
                int sl = atomicAdd(cnt + d, 1);
                if (sl < 63) csrB[((size_t)d << 6) + 1 + sl] = edge_index[k];
            }
        }
    }
}

// xh (layer 1): reads h from global. Unchanged.
__global__ __launch_bounds__(256) void k_xh1(
        const float* __restrict__ h, const float* __restrict__ wt,
        const float* __restrict__ uv_l, __half* __restrict__ xh,
        float* __restrict__ as_, float* __restrict__ ad_, int N) {
    __shared__ float hs[32][XPAD];
    int t = threadIdx.x;
    int n0 = blockIdx.x * 32;
    for (int i = t; i < 32 * 64; i += 256) {
        int r = i >> 6, c = i & 63;
        int n = n0 + r;
        hs[r][c] = (n < N) ? h[(size_t)n * 64 + c] : 0.f;
    }
    __syncthreads();
    int co4 = (t & 63) * 4;
    int nsub = t >> 6;
    float4 acc[8];
#pragma unroll
    for (int j = 0; j < 8; ++j) acc[j] = make_float4(0.f, 0.f, 0.f, 0.f);
    const float* wp = wt + co4;
#pragma unroll 2
    for (int k4 = 0; k4 < 16; ++k4) {
        float4 w0 = *(const float4*)(wp + (k4 * 4 + 0) * 256);
        float4 w1 = *(const float4*)(wp + (k4 * 4 + 1) * 256);
        float4 w2 = *(const float4*)(wp + (k4 * 4 + 2) * 256);
        float4 w3 = *(const float4*)(wp + (k4 * 4 + 3) * 256);
#pragma unroll
        for (int j = 0; j < 8; ++j) {
            float4 hv = *(const float4*)&hs[nsub * 8 + j][k4 * 4];
            float4 a = acc[j];
            a.x = fmaf(hv.x, w0.x, fmaf(hv.y, w1.x, fmaf(hv.z, w2.x, fmaf(hv.w, w3.x, a.x))));
            a.y = fmaf(hv.x, w0.y, fmaf(hv.y, w1.y, fmaf(hv.z, w2.y, fmaf(hv.w, w3.y, a.y))));
            a.z = fmaf(hv.x, w0.z, fmaf(hv.y, w1.z, fmaf(hv.z, w2.z, fmaf(hv.w, w3.z, a.z))));
            a.w = fmaf(hv.x, w0.w, fmaf(hv.y, w1.w, fmaf(hv.z, w2.w, fmaf(hv.w, w3.w, a.w))));
            acc[j] = a;
        }
    }
#pragma unroll
    for (int j = 0; j < 8; ++j) {
        int n = n0 + nsub * 8 + j;
        if (n < N) {
            h16x4 o;
            o.x = __float2half(acc[j].x);
            o.y = __float2half(acc[j].y);
            o.z = __float2half(acc[j].z);
            o.w = __float2half(acc[j].w);
            *(h16x4*)(xh + (size_t)n * 256 + co4) = o;
        }
    }
    {
        int row  = t >> 3;
        int head = (t >> 1) & 3;
        int sd   = t & 1;
        int n = n0 + row;
        if (n < N) {
            const float* u = uv_l + sd * 256 + head * 64;
            float a = 0.f;
#pragma unroll
            for (int k4 = 0; k4 < 16; ++k4) {
                float4 hv = *(const float4*)&hs[row][k4 * 4];
                float4 uu = *(const float4*)(u + k4 * 4);
                a += hv.x * uu.x + hv.y * uu.y + hv.z * uu.z + hv.w * uu.w;
            }
            (sd ? ad_ : as_)[n * 4 + head] = a;
        }
    }
}

__device__ __forceinline__ __half2 shxor_h2(__half2 a, int m) {
    int u = __shfl_xor(*(int*)&a, m, 64);
    return *(__half2*)&u;
}

// One wave per dst node; 16 lanes/edge; 3-stage pipeline x2 (8 edges/trip).
// Implicit self-loop in slot 0. 32-bit byte-offset addressing.
// LAST: output projection via LDS-staged owT/hout. (Unchanged.)
template <bool LAST>
__global__ __launch_bounds__(256) void k_gat(
        const __half* __restrict__ xh, const float* __restrict__ as_,
        const float* __restrict__ ad_, const int* __restrict__ cnt,
        const int* __restrict__ csrB, const float* __restrict__ convb,
        const float* __restrict__ ln_g, const float* __restrict__ ln_b,
        float* __restrict__ h, const float* __restrict__ owT,
        const float* __restrict__ out_b, float* __restrict__ out, int N) {
    __shared__ float owT_lds[2048];
    __shared__ float hout_lds4[4][64];
    int t = threadIdx.x;
    int wid = t >> 6, lane = t & 63;
    if (LAST) {
        for (int i = t; i < 2048; i += 256) owT_lds[i] = owT[i];
        __syncthreads();
    }
    int n = blockIdx.x * 4 + wid;
    if (n >= N) return;
    float* hout_lds = hout_lds4[wid];
    int g    = lane >> 4;
    int l16  = lane & 15;
    int head = l16 >> 2;
    int r0 = n << 6;
    int r1 = r0 + 1 + min(cnt[n], 63);
    float adv = ad_[(size_t)n * 4 + head];
    const char* xbb = (const char*)xh + (l16 << 5);
    const char* asb = (const char*)as_ + (head << 2);
    const char* cbb = (const char*)csrB;

    float s = 0.f;
    __half2 acc[8];
#pragma unroll
    for (int j = 0; j < 8; ++j) acc[j] = __float2half2_rn(0.f);

    uint4 zero4 = make_uint4(0u, 0u, 0u, 0u);
    int idx;
    idx = r0 + g;      bool vA = idx < r1; int sA = n; if (g != 0 && vA) sA = *(const int*)(cbb + ((unsigned)idx << 2));
    idx = r0 + 4 + g;  bool vB = idx < r1; int sB = 0; if (vB) sB = *(const int*)(cbb + ((unsigned)idx << 2));
    idx = r0 + 8 + g;  bool vC = idx < r1; int sC = 0; if (vC) sC = *(const int*)(cbb + ((unsigned)idx << 2));
    idx = r0 + 12 + g; bool vD = idx < r1; int sD = 0; if (vD) sD = *(const int*)(cbb + ((unsigned)idx << 2));
    float asA = 0.f, asB = 0.f;
    uint4 qA0 = zero4, qA1 = zero4, qB0 = zero4, qB1 = zero4;
    if (vA) {
        asA = *(const float*)(asb + ((unsigned)sA << 4));
        const uint4* bp = (const uint4*)(xbb + ((unsigned)sA << 9));
        qA0 = bp[0]; qA1 = bp[1];
    }
    if (vB) {
        asB = *(const float*)(asb + ((unsigned)sB << 4));
        const uint4* bp = (const uint4*)(xbb + ((unsigned)sB << 9));
        qB0 = bp[0]; qB1 = bp[1];
    }

    auto COMPUTE = [&](bool vc, float asc, const uint4& q0, const uint4& q1) {
        float e = asc + adv;
        e = e > 0.f ? e : NEG_SLOPE * e;
        float w = __expf(e);
        w = vc ? w : 0.f;
        s += w;
        __half2 w2 = __float2half2_rn(w);
        const __half2* ha = (const __half2*)&q0;
        const __half2* hb = (const __half2*)&q1;
        acc[0] = __hfma2(w2, ha[0], acc[0]);
        acc[1] = __hfma2(w2, ha[1], acc[1]);
        acc[2] = __hfma2(w2, ha[2], acc[2]);
        acc[3] = __hfma2(w2, ha[3], acc[3]);
        acc[4] = __hfma2(w2, hb[0], acc[4]);
        acc[5] = __hfma2(w2, hb[1], acc[5]);
        acc[6] = __hfma2(w2, hb[2], acc[6]);
        acc[7] = __hfma2(w2, hb[3], acc[7]);
    };

    for (int i = r0; i < r1; i += 8) {
        COMPUTE(vA, asA, qA0, qA1);
        int idxE = i + 16 + g; bool vE = idxE < r1; int sE = 0;
        if (vE) sE = *(const int*)(cbb + ((unsigned)idxE << 2));
        vA = vC;
        if (vC) {
            asA = *(const float*)(asb + ((unsigned)sC << 4));
            const uint4* bp = (const uint4*)(xbb + ((unsigned)sC << 9));
            qA0 = bp[0]; qA1 = bp[1];
        }
        COMPUTE(vB, asB, qB0, qB1);
        int idxF = i + 20 + g; bool vF = idxF < r1; int sF = 0;
        if (vF) sF = *(const int*)(cbb + ((unsigned)idxF << 2));
        vB = vD;
        if (vD) {
            asB = *(const float*)(asb + ((unsigned)sD << 4));
            const uint4* bp = (const uint4*)(xbb + ((unsigned)sD << 9));
            qB0 = bp[0]; qB1 = bp[1];
        }
        vC = vE; sC = sE;
        vD = vF; sD = sF;
    }

    s += __shfl_xor(s, 16, 64);
    s += __shfl_xor(s, 32, 64);
#pragma unroll
    for (int j = 0; j < 8; ++j) {
        acc[j] = __hadd2(acc[j], shxor_h2(acc[j], 16));
        acc[j] = __hadd2(acc[j], shxor_h2(acc[j], 32));
    }
    float inv = 1.f / (s + 1e-16f);
    __half2 ih = __float2half2_rn(inv);
#pragma unroll
    for (int j = 0; j < 8; ++j) {
        acc[j] = __hmul2(acc[j], ih);
        acc[j] = __hadd2(acc[j], shxor_h2(acc[j], 4));
        acc[j] = __hadd2(acc[j], shxor_h2(acc[j], 8));
    }
    float f[16];
#pragma unroll
    for (int j = 0; j < 8; ++j) {
        float2 tv = __half22float2(acc[j]);
        f[2 * j]     = tv.x;
        f[2 * j + 1] = tv.y;
    }
    int cblk = lane & 3;
    int cb16 = cblk * 16;
    float o[16];
    float part = 0.f;
#pragma unroll
    for (int q = 0; q < 4; ++q) {
        float4 cb = *(const float4*)(convb + cb16 + q * 4);
        o[q * 4 + 0] = 0.25f * f[q * 4 + 0] + cb.x;
        o[q * 4 + 1] = 0.25f * f[q * 4 + 1] + cb.y;
        o[q * 4 + 2] = 0.25f * f[q * 4 + 2] + cb.z;
        o[q * 4 + 3] = 0.25f * f[q * 4 + 3] + cb.w;
        part += o[q * 4 + 0] + o[q * 4 + 1] + o[q * 4 + 2] + o[q * 4 + 3];
    }
    part += __shfl_xor(part, 1, 64);
    part += __shfl_xor(part, 2, 64);
    float mu = part * (1.f / 64.f);
    float vs = 0.f;
#pragma unroll
    for (int j = 0; j < 16; ++j) { o[j] -= mu; vs += o[j] * o[j]; }
    vs += __shfl_xor(vs, 1, 64);
    vs += __shfl_xor(vs, 2, 64);
    float rstd = rsqrtf(vs * (1.f / 64.f) + LN_EPS);

    if (!LAST) {
        if (lane < 4) {
            float4* hp = (float4*)(h + (size_t)n * 64 + cb16);
#pragma unroll
            for (int q = 0; q < 4; ++q) {
                float4 hv = hp[q];
                float4 gv = *(const float4*)(ln_g + cb16 + q * 4);
                float4 bv = *(const float4*)(ln_b + cb16 + q * 4);
                hv.x += fmaxf(o[q * 4 + 0] * rstd * gv.x + bv.x, 0.f);
                hv.y += fmaxf(o[q * 4 + 1] * rstd * gv.y + bv.y, 0.f);
                hv.z += fmaxf(o[q * 4 + 2] * rstd * gv.z + bv.z, 0.f);
                hv.w += fmaxf(o[q * 4 + 3] * rstd * gv.w + bv.w, 0.f);
                hp[q] = hv;
            }
        }
    } else {
        if (lane < 4) {
            const float4* hp = (const float4*)(h + (size_t)n * 64 + cb16);
#pragma unroll
            for (int q = 0; q < 4; ++q) {
                float4 hv = hp[q];
                float4 gv = *(const float4*)(ln_g + cb16 + q * 4);
                float4 bv = *(const float4*)(ln_b + cb16 + q * 4);
                hout_lds[cb16 + q * 4 + 0] = hv.x + fmaxf(o[q * 4 + 0] * rstd * gv.x + bv.x, 0.f);
                hout_lds[cb16 + q * 4 + 1] = hv.y + fmaxf(o[q * 4 + 1] * rstd * gv.y + bv.y, 0.f);
                hout_lds[cb16 + q * 4 + 2] = hv.z + fmaxf(o[q * 4 + 2] * rstd * gv.z + bv.z, 0.f);
                hout_lds[cb16 + q * 4 + 3] = hv.w + fmaxf(o[q * 4 + 3] * rstd * gv.w + bv.w, 0.f);
            }
        }
        asm volatile("s_waitcnt lgkmcnt(0)" ::: "memory");
        if (lane < 32) {
            float acc2 = out_b[lane];
#pragma unroll 8
            for (int k = 0; k < 64; ++k)
                acc2 = fmaf(hout_lds[k], owT_lds[k * 32 + lane], acc2);
            out[(size_t)n * 32 + lane] = acc2;
        }
    }
}

static inline unsigned cdiv(long long a, long long b) { return (unsigned)((a + b - 1) / b); }

extern "C" void kernel_launch(void* const* d_in, const int* in_sizes, int n_in,
                              void* d_out, int out_size, void* d_ws, size_t ws_size,
                              hipStream_t stream) {
    const float* x          = (const float*)d_in[0];
    const float* drone_feat = (const float*)d_in[1];
    const int*   edge_index = (const int*)d_in[2];
    const int*   batch      = (const int*)d_in[3];
    const float* node_W     = (const float*)d_in[4];
    const float* node_b     = (const float*)d_in[5];
    const float* drone_W    = (const float*)d_in[6];
    const float* drone_b    = (const float*)d_in[7];
    const float* convW[2]   = {(const float*)d_in[8],  (const float*)d_in[14]};
    const float* att_src[2] = {(const float*)d_in[9],  (const float*)d_in[15]};
    const float* att_dst[2] = {(const float*)d_in[10], (const float*)d_in[16]};
    const float* convb[2]   = {(const float*)d_in[11], (const float*)d_in[17]};
    const float* ln_g[2]    = {(const float*)d_in[12], (const float*)d_in[18]};
    const float* ln_b[2]    = {(const float*)d_in[13], (const float*)d_in[19]};
    const float* out_W      = (const float*)d_in[20];
    const float* out_b      = (const float*)d_in[21];
    float* out = (float*)d_out;

    const int N = in_sizes[0] / 32;
    const int E = in_sizes[2] / 2;
    const int P = 8;                        // scatter passes
    const int S = cdiv(N, P);               // dst range per pass
    const int NS = cdiv(cdiv(E, 4), 256);   // scatter blocks per pass
    const int NXH = cdiv(N, 32);            // xh-role blocks (placed FIRST)

    char* base = (char*)d_ws;
    size_t off = 0;
    auto alloc = [&](size_t bytes) {
        char* p = base + off;
        off = (off + bytes + 255) & ~(size_t)255;
        return p;
    };
    float*           h      = (float*)alloc((size_t)N * 64 * 4);
    __half*          xh     = (__half*)alloc((size_t)N * 256 * 2);
    float*           as_    = (float*)alloc((size_t)N * 4 * 4);
    float*           ad_    = (float*)alloc((size_t)N * 4 * 4);
    float*           wt0    = (float*)alloc((size_t)256 * 64 * 4);
    float*           wt1    = (float*)alloc((size_t)256 * 64 * 4);
    float*           uv     = (float*)alloc((size_t)1024 * 4);
    float*           owT    = (float*)alloc((size_t)2048 * 4);
    int*             cnt    = (int*)alloc((size_t)N * 4);
    int*             csrB   = (int*)alloc((size_t)N * 64 * 4);
    (void)ws_size;

    // D1: cnt=0 + layer-0 weight prep (wt0, uv0)
    k_init<<<cdiv(N, 256), 256, 0, stream>>>(convW[0], att_src[0], att_dst[0],
                                             wt0, uv, cnt, N);
    // D2: merged {layer-0 xh (h0 fused), FIRST} || {8-pass windowed scatter + prep}
    k_sx<<<NXH + NS * P, 256, 0, stream>>>(
        edge_index, cnt, csrB,
        convW[1], att_src[1], att_dst[1], out_W,
        wt1, uv, owT, E, S, NS, NXH,
        wt0, xh, as_, ad_,
        x, batch, node_W, drone_W, node_b, drone_b, drone_feat, h, N);
    // D3-D5: gat0, xh1, gat1 (final gat fuses the output projection)
    k_gat<false><<<cdiv(N, 4), 256, 0, stream>>>(xh, as_, ad_, cnt, csrB, convb[0],
                                                 ln_g[0], ln_b[0], h, owT, out_b, out, N);
    k_xh1<<<cdiv(N, 32), 256, 0, stream>>>(h, wt1, uv + 512, xh, as_, ad_, N);
    k_gat<true><<<cdiv(N, 4), 256, 0, stream>>>(xh, as_, ad_, cnt, csrB, convb[1],
                                                ln_g[1], ln_b[1], h, owT, out_b, out, N);
}

// Round 16
// 610.276 us; speedup vs baseline: 1.0259x; 1.0092x over previous
//
#include <hip/hip_runtime.h>
#include <hip/hip_fp16.h>
#include <math.h>

// N=100000, E=1600000, G=64, H=4, C=64, NODE_F=32, DRONE_F=16, OUT=32, L=2

#define NEG_SLOPE 0.2f
#define LN_EPS 1e-5f

struct __align__(8) h16x4 { __half x, y, z, w; };

// cnt=0 + layer-0 weight prep (wt0 transpose, uv0). Replaces the memset slot.
__global__ __launch_bounds__(256) void k_init(
        const float* __restrict__ cW0, const float* __restrict__ s0,
        const float* __restrict__ d0, float* __restrict__ wt0,
        float* __restrict__ uv, int* __restrict__ cnt, int N) {
    int i = blockIdx.x * 256 + threadIdx.x;
    if (i < N) cnt[i] = 0;
    if (i < 16384) { int co = i >> 6, k = i & 63; wt0[k * 256 + co] = cW0[i]; }
    if (i < 512) {
        int sd = (i >> 8) & 1, head = (i >> 6) & 3, kk = i & 63;
        const float* att = sd ? d0 : s0;
        float acc = 0.f;
        for (int c = 0; c < 64; ++c)
            acc += cW0[(head * 64 + c) * 64 + kk] * att[head * 64 + c];
        uv[i] = acc;
    }
}

#define XPAD 68

// xh layer-0 block body (h0 fused). LDS-diet: h0 result to registers,
// hs[32][68] aliased over the dead wn/wd region -> 19136 B total.
__device__ __forceinline__ void xh0_block(
        int n0, const float* __restrict__ wt, const float* __restrict__ uv_l,
        __half* __restrict__ xh, float* __restrict__ as_, float* __restrict__ ad_,
        const float* __restrict__ x, const int* __restrict__ batch,
        const float* __restrict__ node_W, const float* __restrict__ drone_W,
        const float* __restrict__ node_b, const float* __restrict__ drone_b,
        const float* __restrict__ drone_feat, float* __restrict__ h_out, int N,
        float* smem_f) {
    float (*wn)[65] = (float(*)[65])smem_f;
    float (*wd)[65] = (float(*)[65])(smem_f + 2080);
    float* bs = smem_f + 3120;
    float (*xs)[33] = (float(*)[33])(smem_f + 3184);
    float (*ds)[17] = (float(*)[17])(smem_f + 4240);
    float (*hs)[XPAD] = (float(*)[XPAD])smem_f;
    int t = threadIdx.x;
    for (int i = t; i < 2048; i += 256) { int co = i >> 5, k = i & 31; wn[k][co] = node_W[i]; }
    for (int i = t; i < 1024; i += 256) { int co = i >> 4, k = i & 15; wd[k][co] = drone_W[i]; }
    if (t < 64) bs[t] = node_b[t] + drone_b[t];
    for (int i = t; i < 1024; i += 256) {
        int r = i >> 5, c = i & 31;
        int n = n0 + r;
        xs[r][c] = (n < N) ? x[(size_t)n * 32 + c] : 0.f;
    }
    for (int i = t; i < 512; i += 256) {
        int r = i >> 4, c = i & 15;
        int n = n0 + r;
        int g = (n < N) ? batch[n] : 0;
        ds[r][c] = drone_feat[g * 16 + c];
    }
    __syncthreads();
    int co = t & 63, nsub = t >> 6;
    float a[8];
    {
        float b = bs[co];
#pragma unroll
        for (int j = 0; j < 8; ++j) {
            int r = nsub * 8 + j;
            float acc = b;
#pragma unroll
            for (int k = 0; k < 32; ++k) acc = fmaf(xs[r][k], wn[k][co], acc);
#pragma unroll
            for (int k = 0; k < 16; ++k) acc = fmaf(ds[r][k], wd[k][co], acc);
            a[j] = acc;
        }
    }
    __syncthreads();   // all reads of wn/wd/xs/ds done -> safe to overlay hs
#pragma unroll
    for (int j = 0; j < 8; ++j) {
        int r = nsub * 8 + j;
        hs[r][co] = a[j];
        int n = n0 + r;
        if (n < N) h_out[(size_t)n * 64 + co] = a[j];
    }
    __syncthreads();
    int co4 = (t & 63) * 4;
    float4 acc[8];
#pragma unroll
    for (int j = 0; j < 8; ++j) acc[j] = make_float4(0.f, 0.f, 0.f, 0.f);
    const float* wp = wt + co4;
#pragma unroll 2
    for (int k4 = 0; k4 < 16; ++k4) {
        float4 w0 = *(const float4*)(wp + (k4 * 4 + 0) * 256);
        float4 w1 = *(const float4*)(wp + (k4 * 4 + 1) * 256);
        float4 w2 = *(const float4*)(wp + (k4 * 4 + 2) * 256);
        float4 w3 = *(const float4*)(wp + (k4 * 4 + 3) * 256);
#pragma unroll
        for (int j = 0; j < 8; ++j) {
            float4 hv = *(const float4*)&hs[nsub * 8 + j][k4 * 4];
            float4 v = acc[j];
            v.x = fmaf(hv.x, w0.x, fmaf(hv.y, w1.x, fmaf(hv.z, w2.x, fmaf(hv.w, w3.x, v.x))));
            v.y = fmaf(hv.x, w0.y, fmaf(hv.y, w1.y, fmaf(hv.z, w2.y, fmaf(hv.w, w3.y, v.y))));
            v.z = fmaf(hv.x, w0.z, fmaf(hv.y, w1.z, fmaf(hv.z, w2.z, fmaf(hv.w, w3.z, v.z))));
            v.w = fmaf(hv.x, w0.w, fmaf(hv.y, w1.w, fmaf(hv.z, w2.w, fmaf(hv.w, w3.w, v.w))));
            acc[j] = v;
        }
    }
#pragma unroll
    for (int j = 0; j < 8; ++j) {
        int n = n0 + nsub * 8 + j;
        if (n < N) {
            h16x4 o;
            o.x = __float2half(acc[j].x);
            o.y = __float2half(acc[j].y);
            o.z = __float2half(acc[j].z);
            o.w = __float2half(acc[j].w);
            *(h16x4*)(xh + (size_t)n * 256 + co4) = o;
        }
    }
    {
        int row  = t >> 3;
        int head = (t >> 1) & 3;
        int sd   = t & 1;
        int n = n0 + row;
        if (n < N) {
            const float* u = uv_l + sd * 256 + head * 64;
            float av = 0.f;
#pragma unroll
            for (int k4 = 0; k4 < 16; ++k4) {
                float4 hv = *(const float4*)&hs[row][k4 * 4];
                float4 uu = *(const float4*)(u + k4 * 4);
                av += hv.x * uu.x + hv.y * uu.y + hv.z * uu.z + hv.w * uu.w;
            }
            (sd ? ad_ : as_)[n * 4 + head] = av;
        }
    }
}

// Merged kernel: xh-role blocks FIRST [0, NXH); scatter blocks behind.
// Scatter: per pass load ONLY the dst int4; src fetched with a predicated
// scalar load inside the window test (1/8 hit rate) — halves the 8-pass
// L2/L3 read traffic (~205MB -> ~115MB) vs loading both int4 streams.
__global__ __launch_bounds__(256) void k_sx(
        const int* __restrict__ edge_index, int* __restrict__ cnt,
        int* __restrict__ csrB,
        const float* __restrict__ cW1, const float* __restrict__ s1,
        const float* __restrict__ d1, const float* __restrict__ out_W,
        float* __restrict__ wt1, float* __restrict__ uv, float* __restrict__ owT,
        int E, int S, int NS, int NXH,
        const float* __restrict__ wt0, __half* __restrict__ xh,
        float* __restrict__ as_, float* __restrict__ ad_,
        const float* __restrict__ x, const int* __restrict__ batch,
        const float* __restrict__ node_W, const float* __restrict__ drone_W,
        const float* __restrict__ node_b, const float* __restrict__ drone_b,
        const float* __restrict__ drone_feat, float* __restrict__ h_out, int N) {
    __shared__ float smem_f[4784];   // 19136 B
    int bid = blockIdx.x;
    if (bid < NXH) {
        xh0_block(bid * 32, wt0, uv, xh, as_, ad_, x, batch, node_W, drone_W,
                  node_b, drone_b, drone_feat, h_out, N, smem_f);
        return;
    }
    int sb = bid - NXH;
    if (sb < 128) {
        int i = sb * 256 + threadIdx.x;   // 0..32767
        if (i < 16384) { int co = i >> 6, k = i & 63; wt1[k * 256 + co] = cW1[i]; }
        if (i < 2048) { int k = i >> 5, o = i & 31; owT[i] = out_W[o * 64 + k]; }
        if (i < 512) {
            int sd = (i >> 8) & 1, head = (i >> 6) & 3, kk = i & 63;
            const float* att = sd ? d1 : s1;
            float acc = 0.f;
            for (int c = 0; c < 64; ++c)
                acc += cW1[(head * 64 + c) * 64 + kk] * att[head * 64 + c];
            uv[512 + i] = acc;
        }
    }
    int pass = sb / NS, bx = sb - pass * NS;
    int lo = pass * S, hi = lo + S;
    int i = (bx * 256 + threadIdx.x) * 4;
    if (i + 3 < E) {
        int4 dv = *(const int4*)(edge_index + E + i);
        int sl;
        if (dv.x >= lo && dv.x < hi) { int sx = edge_index[i + 0]; sl = atomicAdd(cnt + dv.x, 1); if (sl < 63) csrB[((size_t)dv.x << 6) + 1 + sl] = sx; }
        if (dv.y >= lo && dv.y < hi) { int sy = edge_index[i + 1]; sl = atomicAdd(cnt + dv.y, 1); if (sl < 63) csrB[((size_t)dv.y << 6) + 1 + sl] = sy; }
        if (dv.z >= lo && dv.z < hi) { int sz = edge_index[i + 2]; sl = atomicAdd(cnt + dv.z, 1); if (sl < 63) csrB[((size_t)dv.z << 6) + 1 + sl] = sz; }
        if (dv.w >= lo && dv.w < hi) { int sw = edge_index[i + 3]; sl = atomicAdd(cnt + dv.w, 1); if (sl < 63) csrB[((size_t)dv.w << 6) + 1 + sl] = sw; }
    } else {
        for (int k = i; k < E; ++k) {
            int d = edge_index[E + k];
            if (d >= lo && d < hi) {
                int sl = atomicAdd(cnt + d, 1);
                if (sl < 63) csrB[((size_t)d << 6) + 1 + sl] = edge_index[k];
            }
        }
    }
}

// xh (layer 1): reads h from global. Unchanged.
__global__ __launch_bounds__(256) void k_xh1(
        const float* __restrict__ h, const float* __restrict__ wt,
        const float* __restrict__ uv_l, __half* __restrict__ xh,
        float* __restrict__ as_, float* __restrict__ ad_, int N) {
    __shared__ float hs[32][XPAD];
    int t = threadIdx.x;
    int n0 = blockIdx.x * 32;
    for (int i = t; i < 32 * 64; i += 256) {
        int r = i >> 6, c = i & 63;
        int n = n0 + r;
        hs[r][c] = (n < N) ? h[(size_t)n * 64 + c] : 0.f;
    }
    __syncthreads();
    int co4 = (t & 63) * 4;
    int nsub = t >> 6;
    float4 acc[8];
#pragma unroll
    for (int j = 0; j < 8; ++j) acc[j] = make_float4(0.f, 0.f, 0.f, 0.f);
    const float* wp = wt + co4;
#pragma unroll 2
    for (int k4 = 0; k4 < 16; ++k4) {
        float4 w0 = *(const float4*)(wp + (k4 * 4 + 0) * 256);
        float4 w1 = *(const float4*)(wp + (k4 * 4 + 1) * 256);
        float4 w2 = *(const float4*)(wp + (k4 * 4 + 2) * 256);
        float4 w3 = *(const float4*)(wp + (k4 * 4 + 3) * 256);
#pragma unroll
        for (int j = 0; j < 8; ++j) {
            float4 hv = *(const float4*)&hs[nsub * 8 + j][k4 * 4];
            float4 a = acc[j];
            a.x = fmaf(hv.x, w0.x, fmaf(hv.y, w1.x, fmaf(hv.z, w2.x, fmaf(hv.w, w3.x, a.x))));
            a.y = fmaf(hv.x, w0.y, fmaf(hv.y, w1.y, fmaf(hv.z, w2.y, fmaf(hv.w, w3.y, a.y))));
            a.z = fmaf(hv.x, w0.z, fmaf(hv.y, w1.z, fmaf(hv.z, w2.z, fmaf(hv.w, w3.z, a.z))));
            a.w = fmaf(hv.x, w0.w, fmaf(hv.y, w1.w, fmaf(hv.z, w2.w, fmaf(hv.w, w3.w, a.w))));
            acc[j] = a;
        }
    }
#pragma unroll
    for (int j = 0; j < 8; ++j) {
        int n = n0 + nsub * 8 + j;
        if (n < N) {
            h16x4 o;
            o.x = __float2half(acc[j].x);
            o.y = __float2half(acc[j].y);
            o.z = __float2half(acc[j].z);
            o.w = __float2half(acc[j].w);
            *(h16x4*)(xh + (size_t)n * 256 + co4) = o;
        }
    }
    {
        int row  = t >> 3;
        int head = (t >> 1) & 3;
        int sd   = t & 1;
        int n = n0 + row;
        if (n < N) {
            const float* u = uv_l + sd * 256 + head * 64;
            float a = 0.f;
#pragma unroll
            for (int k4 = 0; k4 < 16; ++k4) {
                float4 hv = *(const float4*)&hs[row][k4 * 4];
                float4 uu = *(const float4*)(u + k4 * 4);
                a += hv.x * uu.x + hv.y * uu.y + hv.z * uu.z + hv.w * uu.w;
            }
            (sd ? ad_ : as_)[n * 4 + head] = a;
        }
    }
}

__device__ __forceinline__ __half2 shxor_h2(__half2 a, int m) {
    int u = __shfl_xor(*(int*)&a, m, 64);
    return *(__half2*)&u;
}

// One wave per dst node; 16 lanes/edge; 3-stage pipeline x2 (8 edges/trip).
// Implicit self-loop in slot 0. 32-bit byte-offset addressing.
// LAST: output projection via LDS-staged owT/hout. (Unchanged.)
template <bool LAST>
__global__ __launch_bounds__(256) void k_gat(
        const __half* __restrict__ xh, const float* __restrict__ as_,
        const float* __restrict__ ad_, const int* __restrict__ cnt,
        const int* __restrict__ csrB, const float* __restrict__ convb,
        const float* __restrict__ ln_g, const float* __restrict__ ln_b,
        float* __restrict__ h, const float* __restrict__ owT,
        const float* __restrict__ out_b, float* __restrict__ out, int N) {
    __shared__ float owT_lds[2048];
    __shared__ float hout_lds4[4][64];
    int t = threadIdx.x;
    int wid = t >> 6, lane = t & 63;
    if (LAST) {
        for (int i = t; i < 2048; i += 256) owT_lds[i] = owT[i];
        __syncthreads();
    }
    int n = blockIdx.x * 4 + wid;
    if (n >= N) return;
    float* hout_lds = hout_lds4[wid];
    int g    = lane >> 4;
    int l16  = lane & 15;
    int head = l16 >> 2;
    int r0 = n << 6;
    int r1 = r0 + 1 + min(cnt[n], 63);
    float adv = ad_[(size_t)n * 4 + head];
    const char* xbb = (const char*)xh + (l16 << 5);
    const char* asb = (const char*)as_ + (head << 2);
    const char* cbb = (const char*)csrB;

    float s = 0.f;
    __half2 acc[8];
#pragma unroll
    for (int j = 0; j < 8; ++j) acc[j] = __float2half2_rn(0.f);

    uint4 zero4 = make_uint4(0u, 0u, 0u, 0u);
    int idx;
    idx = r0 + g;      bool vA = idx < r1; int sA = n; if (g != 0 && vA) sA = *(const int*)(cbb + ((unsigned)idx << 2));
    idx = r0 + 4 + g;  bool vB = idx < r1; int sB = 0; if (vB) sB = *(const int*)(cbb + ((unsigned)idx << 2));
    idx = r0 + 8 + g;  bool vC = idx < r1; int sC = 0; if (vC) sC = *(const int*)(cbb + ((unsigned)idx << 2));
    idx = r0 + 12 + g; bool vD = idx < r1; int sD = 0; if (vD) sD = *(const int*)(cbb + ((unsigned)idx << 2));
    float asA = 0.f, asB = 0.f;
    uint4 qA0 = zero4, qA1 = zero4, qB0 = zero4, qB1 = zero4;
    if (vA) {
        asA = *(const float*)(asb + ((unsigned)sA << 4));
        const uint4* bp = (const uint4*)(xbb + ((unsigned)sA << 9));
        qA0 = bp[0]; qA1 = bp[1];
    }
    if (vB) {
        asB = *(const float*)(asb + ((unsigned)sB << 4));
        const uint4* bp = (const uint4*)(xbb + ((unsigned)sB << 9));
        qB0 = bp[0]; qB1 = bp[1];
    }

    auto COMPUTE = [&](bool vc, float asc, const uint4& q0, const uint4& q1) {
        float e = asc + adv;
        e = e > 0.f ? e : NEG_SLOPE * e;
        float w = __expf(e);
        w = vc ? w : 0.f;
        s += w;
        __half2 w2 = __float2half2_rn(w);
        const __half2* ha = (const __half2*)&q0;
        const __half2* hb = (const __half2*)&q1;
        acc[0] = __hfma2(w2, ha[0], acc[0]);
        acc[1] = __hfma2(w2, ha[1], acc[1]);
        acc[2] = __hfma2(w2, ha[2], acc[2]);
        acc[3] = __hfma2(w2, ha[3], acc[3]);
        acc[4] = __hfma2(w2, hb[0], acc[4]);
        acc[5] = __hfma2(w2, hb[1], acc[5]);
        acc[6] = __hfma2(w2, hb[2], acc[6]);
        acc[7] = __hfma2(w2, hb[3], acc[7]);
    };

    for (int i = r0; i < r1; i += 8) {
        COMPUTE(vA, asA, qA0, qA1);
        int idxE = i + 16 + g; bool vE = idxE < r1; int sE = 0;
        if (vE) sE = *(const int*)(cbb + ((unsigned)idxE << 2));
        vA = vC;
        if (vC) {
            asA = *(const float*)(asb + ((unsigned)sC << 4));
            const uint4* bp = (const uint4*)(xbb + ((unsigned)sC << 9));
            qA0 = bp[0]; qA1 = bp[1];
        }
        COMPUTE(vB, asB, qB0, qB1);
        int idxF = i + 20 + g; bool vF = idxF < r1; int sF = 0;
        if (vF) sF = *(const int*)(cbb + ((unsigned)idxF << 2));
        vB = vD;
        if (vD) {
            asB = *(const float*)(asb + ((unsigned)sD << 4));
            const uint4* bp = (const uint4*)(xbb + ((unsigned)sD << 9));
            qB0 = bp[0]; qB1 = bp[1];
        }
        vC = vE; sC = sE;
        vD = vF; sD = sF;
    }

    s += __shfl_xor(s, 16, 64);
    s += __shfl_xor(s, 32, 64);
#pragma unroll
    for (int j = 0; j < 8; ++j) {
        acc[j] = __hadd2(acc[j], shxor_h2(acc[j], 16));
        acc[j] = __hadd2(acc[j], shxor_h2(acc[j], 32));
    }
    float inv = 1.f / (s + 1e-16f);
    __half2 ih = __float2half2_rn(inv);
#pragma unroll
    for (int j = 0; j < 8; ++j) {
        acc[j] = __hmul2(acc[j], ih);
        acc[j] = __hadd2(acc[j], shxor_h2(acc[j], 4));
        acc[j] = __hadd2(acc[j], shxor_h2(acc[j], 8));
    }
    float f[16];
#pragma unroll
    for (int j = 0; j < 8; ++j) {
        float2 tv = __half22float2(acc[j]);
        f[2 * j]     = tv.x;
        f[2 * j + 1] = tv.y;
    }
    int cblk = lane & 3;
    int cb16 = cblk * 16;
    float o[16];
    float part = 0.f;
#pragma unroll
    for (int q = 0; q < 4; ++q) {
        float4 cb = *(const float4*)(convb + cb16 + q * 4);
        o[q * 4 + 0] = 0.25f * f[q * 4 + 0] + cb.x;
        o[q * 4 + 1] = 0.25f * f[q * 4 + 1] + cb.y;
        o[q * 4 + 2] = 0.25f * f[q * 4 + 2] + cb.z;
        o[q * 4 + 3] = 0.25f * f[q * 4 + 3] + cb.w;
        part += o[q * 4 + 0] + o[q * 4 + 1] + o[q * 4 + 2] + o[q * 4 + 3];
    }
    part += __shfl_xor(part, 1, 64);
    part += __shfl_xor(part, 2, 64);
    float mu = part * (1.f / 64.f);
    float vs = 0.f;
#pragma unroll
    for (int j = 0; j < 16; ++j) { o[j] -= mu; vs += o[j] * o[j]; }
    vs += __shfl_xor(vs, 1, 64);
    vs += __shfl_xor(vs, 2, 64);
    float rstd = rsqrtf(vs * (1.f / 64.f) + LN_EPS);

    if (!LAST) {
        if (lane < 4) {
            float4* hp = (float4*)(h + (size_t)n * 64 + cb16);
#pragma unroll
            for (int q = 0; q < 4; ++q) {
                float4 hv = hp[q];
                float4 gv = *(const float4*)(ln_g + cb16 + q * 4);
                float4 bv = *(const float4*)(ln_b + cb16 + q * 4);
                hv.x += fmaxf(o[q * 4 + 0] * rstd * gv.x + bv.x, 0.f);
                hv.y += fmaxf(o[q * 4 + 1] * rstd * gv.y + bv.y, 0.f);
                hv.z += fmaxf(o[q * 4 + 2] * rstd * gv.z + bv.z, 0.f);
                hv.w += fmaxf(o[q * 4 + 3] * rstd * gv.w + bv.w, 0.f);
                hp[q] = hv;
            }
        }
    } else {
        if (lane < 4) {
            const float4* hp = (const float4*)(h + (size_t)n * 64 + cb16);
#pragma unroll
            for (int q = 0; q < 4; ++q) {
                float4 hv = hp[q];
                float4 gv = *(const float4*)(ln_g + cb16 + q * 4);
                float4 bv = *(const float4*)(ln_b + cb16 + q * 4);
                hout_lds[cb16 + q * 4 + 0] = hv.x + fmaxf(o[q * 4 + 0] * rstd * gv.x + bv.x, 0.f);
                hout_lds[cb16 + q * 4 + 1] = hv.y + fmaxf(o[q * 4 + 1] * rstd * gv.y + bv.y, 0.f);
                hout_lds[cb16 + q * 4 + 2] = hv.z + fmaxf(o[q * 4 + 2] * rstd * gv.z + bv.z, 0.f);
                hout_lds[cb16 + q * 4 + 3] = hv.w + fmaxf(o[q * 4 + 3] * rstd * gv.w + bv.w, 0.f);
            }
        }
        asm volatile("s_waitcnt lgkmcnt(0)" ::: "memory");
        if (lane < 32) {
            float acc2 = out_b[lane];
#pragma unroll 8
            for (int k = 0; k < 64; ++k)
                acc2 = fmaf(hout_lds[k], owT_lds[k * 32 + lane], acc2);
            out[(size_t)n * 32 + lane] = acc2;
        }
    }
}

static inline unsigned cdiv(long long a, long long b) { return (unsigned)((a + b - 1) / b); }

extern "C" void kernel_launch(void* const* d_in, const int* in_sizes, int n_in,
                              void* d_out, int out_size, void* d_ws, size_t ws_size,
                              hipStream_t stream) {
    const float* x          = (const float*)d_in[0];
    const float* drone_feat = (const float*)d_in[1];
    const int*   edge_index = (const int*)d_in[2];
    const int*   batch      = (const int*)d_in[3];
    const float* node_W     = (const float*)d_in[4];
    const float* node_b     = (const float*)d_in[5];
    const float* drone_W    = (const float*)d_in[6];
    const float* drone_b    = (const float*)d_in[7];
    const float* convW[2]   = {(const float*)d_in[8],  (const float*)d_in[14]};
    const float* att_src[2] = {(const float*)d_in[9],  (const float*)d_in[15]};
    const float* att_dst[2] = {(const float*)d_in[10], (const float*)d_in[16]};
    const float* convb[2]   = {(const float*)d_in[11], (const float*)d_in[17]};
    const float* ln_g[2]    = {(const float*)d_in[12], (const float*)d_in[18]};
    const float* ln_b[2]    = {(const float*)d_in[13], (const float*)d_in[19]};
    const float* out_W      = (const float*)d_in[20];
    const float* out_b      = (const float*)d_in[21];
    float* out = (float*)d_out;

    const int N = in_sizes[0] / 32;
    const int E = in_sizes[2] / 2;
    const int P = 8;                        // scatter passes
    const int S = cdiv(N, P);               // dst range per pass
    const int NS = cdiv(cdiv(E, 4), 256);   // scatter blocks per pass
    const int NXH = cdiv(N, 32);            // xh-role blocks (placed FIRST)

    char* base = (char*)d_ws;
    size_t off = 0;
    auto alloc = [&](size_t bytes) {
        char* p = base + off;
        off = (off + bytes + 255) & ~(size_t)255;
        return p;
    };
    float*           h      = (float*)alloc((size_t)N * 64 * 4);
    __half*          xh     = (__half*)alloc((size_t)N * 256 * 2);
    float*           as_    = (float*)alloc((size_t)N * 4 * 4);
    float*           ad_    = (float*)alloc((size_t)N * 4 * 4);
    float*           wt0    = (float*)alloc((size_t)256 * 64 * 4);
    float*           wt1    = (float*)alloc((size_t)256 * 64 * 4);
    float*           uv     = (float*)alloc((size_t)1024 * 4);
    float*           owT    = (float*)alloc((size_t)2048 * 4);
    int*             cnt    = (int*)alloc((size_t)N * 4);
    int*             csrB   = (int*)alloc((size_t)N * 64 * 4);
    (void)ws_size;

    // D1: cnt=0 + layer-0 weight prep (wt0, uv0)
    k_init<<<cdiv(N, 256), 256, 0, stream>>>(convW[0], att_src[0], att_dst[0],
                                             wt0, uv, cnt, N);
    // D2: merged {layer-0 xh (h0 fused), FIRST} || {8-pass windowed scatter + prep}
    k_sx<<<NXH + NS * P, 256, 0, stream>>>(
        edge_index, cnt, csrB,
        convW[1], att_src[1], att_dst[1], out_W,
        wt1, uv, owT, E, S, NS, NXH,
        wt0, xh, as_, ad_,
        x, batch, node_W, drone_W, node_b, drone_b, drone_feat, h, N);
    // D3-D5: gat0, xh1, gat1 (final gat fuses the output projection)
    k_gat<false><<<cdiv(N, 4), 256, 0, stream>>>(xh, as_, ad_, cnt, csrB, convb[0],
                                                 ln_g[0], ln_b[0], h, owT, out_b, out, N);
    k_xh1<<<cdiv(N, 32), 256, 0, stream>>>(h, wt1, uv + 512, xh, as_, ad_, N);
    k_gat<true><<<cdiv(N, 4), 256, 0, stream>>>(xh, as_, ad_, cnt, csrB, convb[1],
                                                ln_g[1], ln_b[1], h, owT, out_b, out, N);
}

// Round 17
// 609.183 us; speedup vs baseline: 1.0277x; 1.0018x over previous
//
#include <hip/hip_runtime.h>
#include <hip/hip_fp16.h>
#include <math.h>

// N=100000, E=1600000, G=64, H=4, C=64, NODE_F=32, DRONE_F=16, OUT=32, L=2

#define NEG_SLOPE 0.2f
#define LN_EPS 1e-5f

struct __align__(8) h16x4 { __half x, y, z, w; };

// cnt=0 + layer-0 weight prep (wt0 transpose, uv0). Replaces the memset slot.
__global__ __launch_bounds__(256) void k_init(
        const float* __restrict__ cW0, const float* __restrict__ s0,
        const float* __restrict__ d0, float* __restrict__ wt0,
        float* __restrict__ uv, int* __restrict__ cnt, int N) {
    int i = blockIdx.x * 256 + threadIdx.x;
    if (i < N) cnt[i] = 0;
    if (i < 16384) { int co = i >> 6, k = i & 63; wt0[k * 256 + co] = cW0[i]; }
    if (i < 512) {
        int sd = (i >> 8) & 1, head = (i >> 6) & 3, kk = i & 63;
        const float* att = sd ? d0 : s0;
        float acc = 0.f;
        for (int c = 0; c < 64; ++c)
            acc += cW0[(head * 64 + c) * 64 + kk] * att[head * 64 + c];
        uv[i] = acc;
    }
}

#define XPAD 68

// xh layer-0 block body (h0 fused). LDS-diet: h0 result to registers,
// hs[32][68] aliased over the dead wn/wd region -> 19136 B total.
__device__ __forceinline__ void xh0_block(
        int n0, const float* __restrict__ wt, const float* __restrict__ uv_l,
        __half* __restrict__ xh, float* __restrict__ as_, float* __restrict__ ad_,
        const float* __restrict__ x, const int* __restrict__ batch,
        const float* __restrict__ node_W, const float* __restrict__ drone_W,
        const float* __restrict__ node_b, const float* __restrict__ drone_b,
        const float* __restrict__ drone_feat, float* __restrict__ h_out, int N,
        float* smem_f) {
    float (*wn)[65] = (float(*)[65])smem_f;
    float (*wd)[65] = (float(*)[65])(smem_f + 2080);
    float* bs = smem_f + 3120;
    float (*xs)[33] = (float(*)[33])(smem_f + 3184);
    float (*ds)[17] = (float(*)[17])(smem_f + 4240);
    float (*hs)[XPAD] = (float(*)[XPAD])smem_f;
    int t = threadIdx.x;
    for (int i = t; i < 2048; i += 256) { int co = i >> 5, k = i & 31; wn[k][co] = node_W[i]; }
    for (int i = t; i < 1024; i += 256) { int co = i >> 4, k = i & 15; wd[k][co] = drone_W[i]; }
    if (t < 64) bs[t] = node_b[t] + drone_b[t];
    for (int i = t; i < 1024; i += 256) {
        int r = i >> 5, c = i & 31;
        int n = n0 + r;
        xs[r][c] = (n < N) ? x[(size_t)n * 32 + c] : 0.f;
    }
    for (int i = t; i < 512; i += 256) {
        int r = i >> 4, c = i & 15;
        int n = n0 + r;
        int g = (n < N) ? batch[n] : 0;
        ds[r][c] = drone_feat[g * 16 + c];
    }
    __syncthreads();
    int co = t & 63, nsub = t >> 6;
    float a[8];
    {
        float b = bs[co];
#pragma unroll
        for (int j = 0; j < 8; ++j) {
            int r = nsub * 8 + j;
            float acc = b;
#pragma unroll
            for (int k = 0; k < 32; ++k) acc = fmaf(xs[r][k], wn[k][co], acc);
#pragma unroll
            for (int k = 0; k < 16; ++k) acc = fmaf(ds[r][k], wd[k][co], acc);
            a[j] = acc;
        }
    }
    __syncthreads();   // all reads of wn/wd/xs/ds done -> safe to overlay hs
#pragma unroll
    for (int j = 0; j < 8; ++j) {
        int r = nsub * 8 + j;
        hs[r][co] = a[j];
        int n = n0 + r;
        if (n < N) h_out[(size_t)n * 64 + co] = a[j];
    }
    __syncthreads();
    int co4 = (t & 63) * 4;
    float4 acc[8];
#pragma unroll
    for (int j = 0; j < 8; ++j) acc[j] = make_float4(0.f, 0.f, 0.f, 0.f);
    const float* wp = wt + co4;
#pragma unroll 2
    for (int k4 = 0; k4 < 16; ++k4) {
        float4 w0 = *(const float4*)(wp + (k4 * 4 + 0) * 256);
        float4 w1 = *(const float4*)(wp + (k4 * 4 + 1) * 256);
        float4 w2 = *(const float4*)(wp + (k4 * 4 + 2) * 256);
        float4 w3 = *(const float4*)(wp + (k4 * 4 + 3) * 256);
#pragma unroll
        for (int j = 0; j < 8; ++j) {
            float4 hv = *(const float4*)&hs[nsub * 8 + j][k4 * 4];
            float4 v = acc[j];
            v.x = fmaf(hv.x, w0.x, fmaf(hv.y, w1.x, fmaf(hv.z, w2.x, fmaf(hv.w, w3.x, v.x))));
            v.y = fmaf(hv.x, w0.y, fmaf(hv.y, w1.y, fmaf(hv.z, w2.y, fmaf(hv.w, w3.y, v.y))));
            v.z = fmaf(hv.x, w0.z, fmaf(hv.y, w1.z, fmaf(hv.z, w2.z, fmaf(hv.w, w3.z, v.z))));
            v.w = fmaf(hv.x, w0.w, fmaf(hv.y, w1.w, fmaf(hv.z, w2.w, fmaf(hv.w, w3.w, v.w))));
            acc[j] = v;
        }
    }
#pragma unroll
    for (int j = 0; j < 8; ++j) {
        int n = n0 + nsub * 8 + j;
        if (n < N) {
            h16x4 o;
            o.x = __float2half(acc[j].x);
            o.y = __float2half(acc[j].y);
            o.z = __float2half(acc[j].z);
            o.w = __float2half(acc[j].w);
            *(h16x4*)(xh + (size_t)n * 256 + co4) = o;
        }
    }
    {
        int row  = t >> 3;
        int head = (t >> 1) & 3;
        int sd   = t & 1;
        int n = n0 + row;
        if (n < N) {
            const float* u = uv_l + sd * 256 + head * 64;
            float av = 0.f;
#pragma unroll
            for (int k4 = 0; k4 < 16; ++k4) {
                float4 hv = *(const float4*)&hs[row * 1 + 0][k4 * 4];
                float4 uu = *(const float4*)(u + k4 * 4);
                av += hv.x * uu.x + hv.y * uu.y + hv.z * uu.z + hv.w * uu.w;
            }
            (sd ? ad_ : as_)[n * 4 + head] = av;
        }
    }
}

// Merged kernel: xh-role blocks FIRST [0, NXH); scatter blocks behind.
// Scatter: P=4 windowed passes (halved scan overhead vs P=8; window 6.4MB
// absorbed by aggregate L2+L3). Conditional scalar src loads kept.
__global__ __launch_bounds__(256) void k_sx(
        const int* __restrict__ edge_index, int* __restrict__ cnt,
        int* __restrict__ csrB,
        const float* __restrict__ cW1, const float* __restrict__ s1,
        const float* __restrict__ d1, const float* __restrict__ out_W,
        float* __restrict__ wt1, float* __restrict__ uv, float* __restrict__ owT,
        int E, int S, int NS, int NXH,
        const float* __restrict__ wt0, __half* __restrict__ xh,
        float* __restrict__ as_, float* __restrict__ ad_,
        const float* __restrict__ x, const int* __restrict__ batch,
        const float* __restrict__ node_W, const float* __restrict__ drone_W,
        const float* __restrict__ node_b, const float* __restrict__ drone_b,
        const float* __restrict__ drone_feat, float* __restrict__ h_out, int N) {
    __shared__ float smem_f[4784];   // 19136 B
    int bid = blockIdx.x;
    if (bid < NXH) {
        xh0_block(bid * 32, wt0, uv, xh, as_, ad_, x, batch, node_W, drone_W,
                  node_b, drone_b, drone_feat, h_out, N, smem_f);
        return;
    }
    int sb = bid - NXH;
    if (sb < 128) {
        int i = sb * 256 + threadIdx.x;   // 0..32767
        if (i < 16384) { int co = i >> 6, k = i & 63; wt1[k * 256 + co] = cW1[i]; }
        if (i < 2048) { int k = i >> 5, o = i & 31; owT[i] = out_W[o * 64 + k]; }
        if (i < 512) {
            int sd = (i >> 8) & 1, head = (i >> 6) & 3, kk = i & 63;
            const float* att = sd ? d1 : s1;
            float acc = 0.f;
            for (int c = 0; c < 64; ++c)
                acc += cW1[(head * 64 + c) * 64 + kk] * att[head * 64 + c];
            uv[512 + i] = acc;
        }
    }
    int pass = sb / NS, bx = sb - pass * NS;
    int lo = pass * S, hi = lo + S;
    int i = (bx * 256 + threadIdx.x) * 4;
    if (i + 3 < E) {
        int4 dv = *(const int4*)(edge_index + E + i);
        int sl;
        if (dv.x >= lo && dv.x < hi) { int sx = edge_index[i + 0]; sl = atomicAdd(cnt + dv.x, 1); if (sl < 63) csrB[((size_t)dv.x << 6) + 1 + sl] = sx; }
        if (dv.y >= lo && dv.y < hi) { int sy = edge_index[i + 1]; sl = atomicAdd(cnt + dv.y, 1); if (sl < 63) csrB[((size_t)dv.y << 6) + 1 + sl] = sy; }
        if (dv.z >= lo && dv.z < hi) { int sz = edge_index[i + 2]; sl = atomicAdd(cnt + dv.z, 1); if (sl < 63) csrB[((size_t)dv.z << 6) + 1 + sl] = sz; }
        if (dv.w >= lo && dv.w < hi) { int sw = edge_index[i + 3]; sl = atomicAdd(cnt + dv.w, 1); if (sl < 63) csrB[((size_t)dv.w << 6) + 1 + sl] = sw; }
    } else {
        for (int k = i; k < E; ++k) {
            int d = edge_index[E + k];
            if (d >= lo && d < hi) {
                int sl = atomicAdd(cnt + d, 1);
                if (sl < 63) csrB[((size_t)d << 6) + 1 + sl] = edge_index[k];
            }
        }
    }
}

// xh (layer 1): reads h from global. Unchanged.
__global__ __launch_bounds__(256) void k_xh1(
        const float* __restrict__ h, const float* __restrict__ wt,
        const float* __restrict__ uv_l, __half* __restrict__ xh,
        float* __restrict__ as_, float* __restrict__ ad_, int N) {
    __shared__ float hs[32][XPAD];
    int t = threadIdx.x;
    int n0 = blockIdx.x * 32;
    for (int i = t; i < 32 * 64; i += 256) {
        int r = i >> 6, c = i & 63;
        int n = n0 + r;
        hs[r][c] = (n < N) ? h[(size_t)n * 64 + c] : 0.f;
    }
    __syncthreads();
    int co4 = (t & 63) * 4;
    int nsub = t >> 6;
    float4 acc[8];
#pragma unroll
    for (int j = 0; j < 8; ++j) acc[j] = make_float4(0.f, 0.f, 0.f, 0.f);
    const float* wp = wt + co4;
#pragma unroll 2
    for (int k4 = 0; k4 < 16; ++k4) {
        float4 w0 = *(const float4*)(wp + (k4 * 4 + 0) * 256);
        float4 w1 = *(const float4*)(wp + (k4 * 4 + 1) * 256);
        float4 w2 = *(const float4*)(wp + (k4 * 4 + 2) * 256);
        float4 w3 = *(const float4*)(wp + (k4 * 4 + 3) * 256);
#pragma unroll
        for (int j = 0; j < 8; ++j) {
            float4 hv = *(const float4*)&hs[nsub * 8 + j][k4 * 4];
            float4 a = acc[j];
            a.x = fmaf(hv.x, w0.x, fmaf(hv.y, w1.x, fmaf(hv.z, w2.x, fmaf(hv.w, w3.x, a.x))));
            a.y = fmaf(hv.x, w0.y, fmaf(hv.y, w1.y, fmaf(hv.z, w2.y, fmaf(hv.w, w3.y, a.y))));
            a.z = fmaf(hv.x, w0.z, fmaf(hv.y, w1.z, fmaf(hv.z, w2.z, fmaf(hv.w, w3.z, a.z))));
            a.w = fmaf(hv.x, w0.w, fmaf(hv.y, w1.w, fmaf(hv.z, w2.w, fmaf(hv.w, w3.w, a.w))));
            acc[j] = a;
        }
    }
#pragma unroll
    for (int j = 0; j < 8; ++j) {
        int n = n0 + nsub * 8 + j;
        if (n < N) {
            h16x4 o;
            o.x = __float2half(acc[j].x);
            o.y = __float2half(acc[j].y);
            o.z = __float2half(acc[j].z);
            o.w = __float2half(acc[j].w);
            *(h16x4*)(xh + (size_t)n * 256 + co4) = o;
        }
    }
    {
        int row  = t >> 3;
        int head = (t >> 1) & 3;
        int sd   = t & 1;
        int n = n0 + row;
        if (n < N) {
            const float* u = uv_l + sd * 256 + head * 64;
            float a = 0.f;
#pragma unroll
            for (int k4 = 0; k4 < 16; ++k4) {
                float4 hv = *(const float4*)&hs[row][k4 * 4];
                float4 uu = *(const float4*)(u + k4 * 4);
                a += hv.x * uu.x + hv.y * uu.y + hv.z * uu.z + hv.w * uu.w;
            }
            (sd ? ad_ : as_)[n * 4 + head] = a;
        }
    }
}

__device__ __forceinline__ __half2 shxor_h2(__half2 a, int m) {
    int u = __shfl_xor(*(int*)&a, m, 64);
    return *(__half2*)&u;
}

// One wave per dst node; 16 lanes/edge; 3-stage pipeline x2 (8 edges/trip).
// Implicit self-loop in slot 0. 32-bit byte-offset addressing.
// LAST: output projection via LDS-staged owT/hout. (Unchanged.)
template <bool LAST>
__global__ __launch_bounds__(256) void k_gat(
        const __half* __restrict__ xh, const float* __restrict__ as_,
        const float* __restrict__ ad_, const int* __restrict__ cnt,
        const int* __restrict__ csrB, const float* __restrict__ convb,
        const float* __restrict__ ln_g, const float* __restrict__ ln_b,
        float* __restrict__ h, const float* __restrict__ owT,
        const float* __restrict__ out_b, float* __restrict__ out, int N) {
    __shared__ float owT_lds[2048];
    __shared__ float hout_lds4[4][64];
    int t = threadIdx.x;
    int wid = t >> 6, lane = t & 63;
    if (LAST) {
        for (int i = t; i < 2048; i += 256) owT_lds[i] = owT[i];
        __syncthreads();
    }
    int n = blockIdx.x * 4 + wid;
    if (n >= N) return;
    float* hout_lds = hout_lds4[wid];
    int g    = lane >> 4;
    int l16  = lane & 15;
    int head = l16 >> 2;
    int r0 = n << 6;
    int r1 = r0 + 1 + min(cnt[n], 63);
    float adv = ad_[(size_t)n * 4 + head];
    const char* xbb = (const char*)xh + (l16 << 5);
    const char* asb = (const char*)as_ + (head << 2);
    const char* cbb = (const char*)csrB;

    float s = 0.f;
    __half2 acc[8];
#pragma unroll
    for (int j = 0; j < 8; ++j) acc[j] = __float2half2_rn(0.f);

    uint4 zero4 = make_uint4(0u, 0u, 0u, 0u);
    int idx;
    idx = r0 + g;      bool vA = idx < r1; int sA = n; if (g != 0 && vA) sA = *(const int*)(cbb + ((unsigned)idx << 2));
    idx = r0 + 4 + g;  bool vB = idx < r1; int sB = 0; if (vB) sB = *(const int*)(cbb + ((unsigned)idx << 2));
    idx = r0 + 8 + g;  bool vC = idx < r1; int sC = 0; if (vC) sC = *(const int*)(cbb + ((unsigned)idx << 2));
    idx = r0 + 12 + g; bool vD = idx < r1; int sD = 0; if (vD) sD = *(const int*)(cbb + ((unsigned)idx << 2));
    float asA = 0.f, asB = 0.f;
    uint4 qA0 = zero4, qA1 = zero4, qB0 = zero4, qB1 = zero4;
    if (vA) {
        asA = *(const float*)(asb + ((unsigned)sA << 4));
        const uint4* bp = (const uint4*)(xbb + ((unsigned)sA << 9));
        qA0 = bp[0]; qA1 = bp[1];
    }
    if (vB) {
        asB = *(const float*)(asb + ((unsigned)sB << 4));
        const uint4* bp = (const uint4*)(xbb + ((unsigned)sB << 9));
        qB0 = bp[0]; qB1 = bp[1];
    }

    auto COMPUTE = [&](bool vc, float asc, const uint4& q0, const uint4& q1) {
        float e = asc + adv;
        e = e > 0.f ? e : NEG_SLOPE * e;
        float w = __expf(e);
        w = vc ? w : 0.f;
        s += w;
        __half2 w2 = __float2half2_rn(w);
        const __half2* ha = (const __half2*)&q0;
        const __half2* hb = (const __half2*)&q1;
        acc[0] = __hfma2(w2, ha[0], acc[0]);
        acc[1] = __hfma2(w2, ha[1], acc[1]);
        acc[2] = __hfma2(w2, ha[2], acc[2]);
        acc[3] = __hfma2(w2, ha[3], acc[3]);
        acc[4] = __hfma2(w2, hb[0], acc[4]);
        acc[5] = __hfma2(w2, hb[1], acc[5]);
        acc[6] = __hfma2(w2, hb[2], acc[6]);
        acc[7] = __hfma2(w2, hb[3], acc[7]);
    };

    for (int i = r0; i < r1; i += 8) {
        COMPUTE(vA, asA, qA0, qA1);
        int idxE = i + 16 + g; bool vE = idxE < r1; int sE = 0;
        if (vE) sE = *(const int*)(cbb + ((unsigned)idxE << 2));
        vA = vC;
        if (vC) {
            asA = *(const float*)(asb + ((unsigned)sC << 4));
            const uint4* bp = (const uint4*)(xbb + ((unsigned)sC << 9));
            qA0 = bp[0]; qA1 = bp[1];
        }
        COMPUTE(vB, asB, qB0, qB1);
        int idxF = i + 20 + g; bool vF = idxF < r1; int sF = 0;
        if (vF) sF = *(const int*)(cbb + ((unsigned)idxF << 2));
        vB = vD;
        if (vD) {
            asB = *(const float*)(asb + ((unsigned)sD << 4));
            const uint4* bp = (const uint4*)(xbb + ((unsigned)sD << 9));
            qB0 = bp[0]; qB1 = bp[1];
        }
        vC = vE; sC = sE;
        vD = vF; sD = sF;
    }

    s += __shfl_xor(s, 16, 64);
    s += __shfl_xor(s, 32, 64);
#pragma unroll
    for (int j = 0; j < 8; ++j) {
        acc[j] = __hadd2(acc[j], shxor_h2(acc[j], 16));
        acc[j] = __hadd2(acc[j], shxor_h2(acc[j], 32));
    }
    float inv = 1.f / (s + 1e-16f);
    __half2 ih = __float2half2_rn(inv);
#pragma unroll
    for (int j = 0; j < 8; ++j) {
        acc[j] = __hmul2(acc[j], ih);
        acc[j] = __hadd2(acc[j], shxor_h2(acc[j], 4));
        acc[j] = __hadd2(acc[j], shxor_h2(acc[j], 8));
    }
    float f[16];
#pragma unroll
    for (int j = 0; j < 8; ++j) {
        float2 tv = __half22float2(acc[j]);
        f[2 * j]     = tv.x;
        f[2 * j + 1] = tv.y;
    }
    int cblk = lane & 3;
    int cb16 = cblk * 16;
    float o[16];
    float part = 0.f;
#pragma unroll
    for (int q = 0; q < 4; ++q) {
        float4 cb = *(const float4*)(convb + cb16 + q * 4);
        o[q * 4 + 0] = 0.25f * f[q * 4 + 0] + cb.x;
        o[q * 4 + 1] = 0.25f * f[q * 4 + 1] + cb.y;
        o[q * 4 + 2] = 0.25f * f[q * 4 + 2] + cb.z;
        o[q * 4 + 3] = 0.25f * f[q * 4 + 3] + cb.w;
        part += o[q * 4 + 0] + o[q * 4 + 1] + o[q * 4 + 2] + o[q * 4 + 3];
    }
    part += __shfl_xor(part, 1, 64);
    part += __shfl_xor(part, 2, 64);
    float mu = part * (1.f / 64.f);
    float vs = 0.f;
#pragma unroll
    for (int j = 0; j < 16; ++j) { o[j] -= mu; vs += o[j] * o[j]; }
    vs += __shfl_xor(vs, 1, 64);
    vs += __shfl_xor(vs, 2, 64);
    float rstd = rsqrtf(vs * (1.f / 64.f) + LN_EPS);

    if (!LAST) {
        if (lane < 4) {
            float4* hp = (float4*)(h + (size_t)n * 64 + cb16);
#pragma unroll
            for (int q = 0; q < 4; ++q) {
                float4 hv = hp[q];
                float4 gv = *(const float4*)(ln_g + cb16 + q * 4);
                float4 bv = *(const float4*)(ln_b + cb16 + q * 4);
                hv.x += fmaxf(o[q * 4 + 0] * rstd * gv.x + bv.x, 0.f);
                hv.y += fmaxf(o[q * 4 + 1] * rstd * gv.y + bv.y, 0.f);
                hv.z += fmaxf(o[q * 4 + 2] * rstd * gv.z + bv.z, 0.f);
                hv.w += fmaxf(o[q * 4 + 3] * rstd * gv.w + bv.w, 0.f);
                hp[q] = hv;
            }
        }
    } else {
        if (lane < 4) {
            const float4* hp = (const float4*)(h + (size_t)n * 64 + cb16);
#pragma unroll
            for (int q = 0; q < 4; ++q) {
                float4 hv = hp[q];
                float4 gv = *(const float4*)(ln_g + cb16 + q * 4);
                float4 bv = *(const float4*)(ln_b + cb16 + q * 4);
                hout_lds[cb16 + q * 4 + 0] = hv.x + fmaxf(o[q * 4 + 0] * rstd * gv.x + bv.x, 0.f);
                hout_lds[cb16 + q * 4 + 1] = hv.y + fmaxf(o[q * 4 + 1] * rstd * gv.y + bv.y, 0.f);
                hout_lds[cb16 + q * 4 + 2] = hv.z + fmaxf(o[q * 4 + 2] * rstd * gv.z + bv.z, 0.f);
                hout_lds[cb16 + q * 4 + 3] = hv.w + fmaxf(o[q * 4 + 3] * rstd * gv.w + bv.w, 0.f);
            }
        }
        asm volatile("s_waitcnt lgkmcnt(0)" ::: "memory");
        if (lane < 32) {
            float acc2 = out_b[lane];
#pragma unroll 8
            for (int k = 0; k < 64; ++k)
                acc2 = fmaf(hout_lds[k], owT_lds[k * 32 + lane], acc2);
            out[(size_t)n * 32 + lane] = acc2;
        }
    }
}

static inline unsigned cdiv(long long a, long long b) { return (unsigned)((a + b - 1) / b); }

extern "C" void kernel_launch(void* const* d_in, const int* in_sizes, int n_in,
                              void* d_out, int out_size, void* d_ws, size_t ws_size,
                              hipStream_t stream) {
    const float* x          = (const float*)d_in[0];
    const float* drone_feat = (const float*)d_in[1];
    const int*   edge_index = (const int*)d_in[2];
    const int*   batch      = (const int*)d_in[3];
    const float* node_W     = (const float*)d_in[4];
    const float* node_b     = (const float*)d_in[5];
    const float* drone_W    = (const float*)d_in[6];
    const float* drone_b    = (const float*)d_in[7];
    const float* convW[2]   = {(const float*)d_in[8],  (const float*)d_in[14]};
    const float* att_src[2] = {(const float*)d_in[9],  (const float*)d_in[15]};
    const float* att_dst[2] = {(const float*)d_in[10], (const float*)d_in[16]};
    const float* convb[2]   = {(const float*)d_in[11], (const float*)d_in[17]};
    const float* ln_g[2]    = {(const float*)d_in[12], (const float*)d_in[18]};
    const float* ln_b[2]    = {(const float*)d_in[13], (const float*)d_in[19]};
    const float* out_W      = (const float*)d_in[20];
    const float* out_b      = (const float*)d_in[21];
    float* out = (float*)d_out;

    const int N = in_sizes[0] / 32;
    const int E = in_sizes[2] / 2;
    const int P = 4;                        // scatter passes (halved from 8)
    const int S = cdiv(N, P);               // dst range per pass
    const int NS = cdiv(cdiv(E, 4), 256);   // scatter blocks per pass
    const int NXH = cdiv(N, 32);            // xh-role blocks (placed FIRST)

    char* base = (char*)d_ws;
    size_t off = 0;
    auto alloc = [&](size_t bytes) {
        char* p = base + off;
        off = (off + bytes + 255) & ~(size_t)255;
        return p;
    };
    float*           h      = (float*)alloc((size_t)N * 64 * 4);
    __half*          xh     = (__half*)alloc((size_t)N * 256 * 2);
    float*           as_    = (float*)alloc((size_t)N * 4 * 4);
    float*           ad_    = (float*)alloc((size_t)N * 4 * 4);
    float*           wt0    = (float*)alloc((size_t)256 * 64 * 4);
    float*           wt1    = (float*)alloc((size_t)256 * 64 * 4);
    float*           uv     = (float*)alloc((size_t)1024 * 4);
    float*           owT    = (float*)alloc((size_t)2048 * 4);
    int*             cnt    = (int*)alloc((size_t)N * 4);
    int*             csrB   = (int*)alloc((size_t)N * 64 * 4);
    (void)ws_size;

    // D1: cnt=0 + layer-0 weight prep (wt0, uv0)
    k_init<<<cdiv(N, 256), 256, 0, stream>>>(convW[0], att_src[0], att_dst[0],
                                             wt0, uv, cnt, N);
    // D2: merged {layer-0 xh (h0 fused), FIRST} || {4-pass windowed scatter + prep}
    k_sx<<<NXH + NS * P, 256, 0, stream>>>(
        edge_index, cnt, csrB,
        convW[1], att_src[1], att_dst[1], out_W,
        wt1, uv, owT, E, S, NS, NXH,
        wt0, xh, as_, ad_,
        x, batch, node_W, drone_W, node_b, drone_b, drone_feat, h, N);
    // D3-D5: gat0, xh1, gat1 (final gat fuses the output projection)
    k_gat<false><<<cdiv(N, 4), 256, 0, stream>>>(xh, as_, ad_, cnt, csrB, convb[0],
                                                 ln_g[0], ln_b[0], h, owT, out_b, out, N);
    k_xh1<<<cdiv(N, 32), 256, 0, stream>>>(h, wt1, uv + 512, xh, as_, ad_, N);
    k_gat<true><<<cdiv(N, 4), 256, 0, stream>>>(xh, as_, ad_, cnt, csrB, convb[1],
                                                ln_g[1], ln_b[1], h, owT, out_b, out, N);
}

// Round 18
// 599.567 us; speedup vs baseline: 1.0442x; 1.0160x over previous
//
#include <hip/hip_runtime.h>
#include <hip/hip_fp16.h>
#include <math.h>

// N=100000, E=1600000, G=64, H=4, C=64, NODE_F=32, DRONE_F=16, OUT=32, L=2

#define NEG_SLOPE 0.2f
#define LN_EPS 1e-5f

struct __align__(8) h16x4 { __half x, y, z, w; };

// cnt=0 + layer-0 weight prep (wt0 transpose, uv0). Replaces the memset slot.
__global__ __launch_bounds__(256) void k_init(
        const float* __restrict__ cW0, const float* __restrict__ s0,
        const float* __restrict__ d0, float* __restrict__ wt0,
        float* __restrict__ uv, int* __restrict__ cnt, int N) {
    int i = blockIdx.x * 256 + threadIdx.x;
    if (i < N) cnt[i] = 0;
    if (i < 16384) { int co = i >> 6, k = i & 63; wt0[k * 256 + co] = cW0[i]; }
    if (i < 512) {
        int sd = (i >> 8) & 1, head = (i >> 6) & 3, kk = i & 63;
        const float* att = sd ? d0 : s0;
        float acc = 0.f;
        for (int c = 0; c < 64; ++c)
            acc += cW0[(head * 64 + c) * 64 + kk] * att[head * 64 + c];
        uv[i] = acc;
    }
}

#define XPAD 68

// xh layer-0 block body (h0 fused). LDS-diet: h0 result to registers,
// hs[32][68] aliased over the dead wn/wd region -> 19136 B total.
__device__ __forceinline__ void xh0_block(
        int n0, const float* __restrict__ wt, const float* __restrict__ uv_l,
        __half* __restrict__ xh, float* __restrict__ as_, float* __restrict__ ad_,
        const float* __restrict__ x, const int* __restrict__ batch,
        const float* __restrict__ node_W, const float* __restrict__ drone_W,
        const float* __restrict__ node_b, const float* __restrict__ drone_b,
        const float* __restrict__ drone_feat, float* __restrict__ h_out, int N,
        float* smem_f) {
    float (*wn)[65] = (float(*)[65])smem_f;
    float (*wd)[65] = (float(*)[65])(smem_f + 2080);
    float* bs = smem_f + 3120;
    float (*xs)[33] = (float(*)[33])(smem_f + 3184);
    float (*ds)[17] = (float(*)[17])(smem_f + 4240);
    float (*hs)[XPAD] = (float(*)[XPAD])smem_f;
    int t = threadIdx.x;
    for (int i = t; i < 2048; i += 256) { int co = i >> 5, k = i & 31; wn[k][co] = node_W[i]; }
    for (int i = t; i < 1024; i += 256) { int co = i >> 4, k = i & 15; wd[k][co] = drone_W[i]; }
    if (t < 64) bs[t] = node_b[t] + drone_b[t];
    for (int i = t; i < 1024; i += 256) {
        int r = i >> 5, c = i & 31;
        int n = n0 + r;
        xs[r][c] = (n < N) ? x[(size_t)n * 32 + c] : 0.f;
    }
    for (int i = t; i < 512; i += 256) {
        int r = i >> 4, c = i & 15;
        int n = n0 + r;
        int g = (n < N) ? batch[n] : 0;
        ds[r][c] = drone_feat[g * 16 + c];
    }
    __syncthreads();
    int co = t & 63, nsub = t >> 6;
    float a[8];
    {
        float b = bs[co];
#pragma unroll
        for (int j = 0; j < 8; ++j) {
            int r = nsub * 8 + j;
            float acc = b;
#pragma unroll
            for (int k = 0; k < 32; ++k) acc = fmaf(xs[r][k], wn[k][co], acc);
#pragma unroll
            for (int k = 0; k < 16; ++k) acc = fmaf(ds[r][k], wd[k][co], acc);
            a[j] = acc;
        }
    }
    __syncthreads();   // all reads of wn/wd/xs/ds done -> safe to overlay hs
#pragma unroll
    for (int j = 0; j < 8; ++j) {
        int r = nsub * 8 + j;
        hs[r][co] = a[j];
        int n = n0 + r;
        if (n < N) h_out[(size_t)n * 64 + co] = a[j];
    }
    __syncthreads();
    int co4 = (t & 63) * 4;
    float4 acc[8];
#pragma unroll
    for (int j = 0; j < 8; ++j) acc[j] = make_float4(0.f, 0.f, 0.f, 0.f);
    const float* wp = wt + co4;
#pragma unroll 2
    for (int k4 = 0; k4 < 16; ++k4) {
        float4 w0 = *(const float4*)(wp + (k4 * 4 + 0) * 256);
        float4 w1 = *(const float4*)(wp + (k4 * 4 + 1) * 256);
        float4 w2 = *(const float4*)(wp + (k4 * 4 + 2) * 256);
        float4 w3 = *(const float4*)(wp + (k4 * 4 + 3) * 256);
#pragma unroll
        for (int j = 0; j < 8; ++j) {
            float4 hv = *(const float4*)&hs[nsub * 8 + j][k4 * 4];
            float4 v = acc[j];
            v.x = fmaf(hv.x, w0.x, fmaf(hv.y, w1.x, fmaf(hv.z, w2.x, fmaf(hv.w, w3.x, v.x))));
            v.y = fmaf(hv.x, w0.y, fmaf(hv.y, w1.y, fmaf(hv.z, w2.y, fmaf(hv.w, w3.y, v.y))));
            v.z = fmaf(hv.x, w0.z, fmaf(hv.y, w1.z, fmaf(hv.z, w2.z, fmaf(hv.w, w3.z, v.z))));
            v.w = fmaf(hv.x, w0.w, fmaf(hv.y, w1.w, fmaf(hv.z, w2.w, fmaf(hv.w, w3.w, v.w))));
            acc[j] = v;
        }
    }
#pragma unroll
    for (int j = 0; j < 8; ++j) {
        int n = n0 + nsub * 8 + j;
        if (n < N) {
            h16x4 o;
            o.x = __float2half(acc[j].x);
            o.y = __float2half(acc[j].y);
            o.z = __float2half(acc[j].z);
            o.w = __float2half(acc[j].w);
            *(h16x4*)(xh + (size_t)n * 256 + co4) = o;
        }
    }
    {
        int row  = t >> 3;
        int head = (t >> 1) & 3;
        int sd   = t & 1;
        int n = n0 + row;
        if (n < N) {
            const float* u = uv_l + sd * 256 + head * 64;
            float av = 0.f;
#pragma unroll
            for (int k4 = 0; k4 < 16; ++k4) {
                float4 hv = *(const float4*)&hs[row][k4 * 4];
                float4 uu = *(const float4*)(u + k4 * 4);
                av += hv.x * uu.x + hv.y * uu.y + hv.z * uu.z + hv.w * uu.w;
            }
            (sd ? ad_ : as_)[n * 4 + head] = av;
        }
    }
}

// Merged kernel: xh-role blocks FIRST [0, NXH); scatter blocks behind (P=4).
__global__ __launch_bounds__(256) void k_sx(
        const int* __restrict__ edge_index, int* __restrict__ cnt,
        int* __restrict__ csrB,
        const float* __restrict__ cW1, const float* __restrict__ s1,
        const float* __restrict__ d1, const float* __restrict__ out_W,
        float* __restrict__ wt1, float* __restrict__ uv, float* __restrict__ owT,
        int E, int S, int NS, int NXH,
        const float* __restrict__ wt0, __half* __restrict__ xh,
        float* __restrict__ as_, float* __restrict__ ad_,
        const float* __restrict__ x, const int* __restrict__ batch,
        const float* __restrict__ node_W, const float* __restrict__ drone_W,
        const float* __restrict__ node_b, const float* __restrict__ drone_b,
        const float* __restrict__ drone_feat, float* __restrict__ h_out, int N) {
    __shared__ float smem_f[4784];   // 19136 B
    int bid = blockIdx.x;
    if (bid < NXH) {
        xh0_block(bid * 32, wt0, uv, xh, as_, ad_, x, batch, node_W, drone_W,
                  node_b, drone_b, drone_feat, h_out, N, smem_f);
        return;
    }
    int sb = bid - NXH;
    if (sb < 128) {
        int i = sb * 256 + threadIdx.x;   // 0..32767
        if (i < 16384) { int co = i >> 6, k = i & 63; wt1[k * 256 + co] = cW1[i]; }
        if (i < 2048) { int k = i >> 5, o = i & 31; owT[i] = out_W[o * 64 + k]; }
        if (i < 512) {
            int sd = (i >> 8) & 1, head = (i >> 6) & 3, kk = i & 63;
            const float* att = sd ? d1 : s1;
            float acc = 0.f;
            for (int c = 0; c < 64; ++c)
                acc += cW1[(head * 64 + c) * 64 + kk] * att[head * 64 + c];
            uv[512 + i] = acc;
        }
    }
    int pass = sb / NS, bx = sb - pass * NS;
    int lo = pass * S, hi = lo + S;
    int i = (bx * 256 + threadIdx.x) * 4;
    if (i + 3 < E) {
        int4 dv = *(const int4*)(edge_index + E + i);
        int sl;
        if (dv.x >= lo && dv.x < hi) { int sx = edge_index[i + 0]; sl = atomicAdd(cnt + dv.x, 1); if (sl < 63) csrB[((size_t)dv.x << 6) + 1 + sl] = sx; }
        if (dv.y >= lo && dv.y < hi) { int sy = edge_index[i + 1]; sl = atomicAdd(cnt + dv.y, 1); if (sl < 63) csrB[((size_t)dv.y << 6) + 1 + sl] = sy; }
        if (dv.z >= lo && dv.z < hi) { int sz = edge_index[i + 2]; sl = atomicAdd(cnt + dv.z, 1); if (sl < 63) csrB[((size_t)dv.z << 6) + 1 + sl] = sz; }
        if (dv.w >= lo && dv.w < hi) { int sw = edge_index[i + 3]; sl = atomicAdd(cnt + dv.w, 1); if (sl < 63) csrB[((size_t)dv.w << 6) + 1 + sl] = sw; }
    } else {
        for (int k = i; k < E; ++k) {
            int d = edge_index[E + k];
            if (d >= lo && d < hi) {
                int sl = atomicAdd(cnt + d, 1);
                if (sl < 63) csrB[((size_t)d << 6) + 1 + sl] = edge_index[k];
            }
        }
    }
}

// xh (layer 1): reads h from global. Unchanged.
__global__ __launch_bounds__(256) void k_xh1(
        const float* __restrict__ h, const float* __restrict__ wt,
        const float* __restrict__ uv_l, __half* __restrict__ xh,
        float* __restrict__ as_, float* __restrict__ ad_, int N) {
    __shared__ float hs[32][XPAD];
    int t = threadIdx.x;
    int n0 = blockIdx.x * 32;
    for (int i = t; i < 32 * 64; i += 256) {
        int r = i >> 6, c = i & 63;
        int n = n0 + r;
        hs[r][c] = (n < N) ? h[(size_t)n * 64 + c] : 0.f;
    }
    __syncthreads();
    int co4 = (t & 63) * 4;
    int nsub = t >> 6;
    float4 acc[8];
#pragma unroll
    for (int j = 0; j < 8; ++j) acc[j] = make_float4(0.f, 0.f, 0.f, 0.f);
    const float* wp = wt + co4;
#pragma unroll 2
    for (int k4 = 0; k4 < 16; ++k4) {
        float4 w0 = *(const float4*)(wp + (k4 * 4 + 0) * 256);
        float4 w1 = *(const float4*)(wp + (k4 * 4 + 1) * 256);
        float4 w2 = *(const float4*)(wp + (k4 * 4 + 2) * 256);
        float4 w3 = *(const float4*)(wp + (k4 * 4 + 3) * 256);
#pragma unroll
        for (int j = 0; j < 8; ++j) {
            float4 hv = *(const float4*)&hs[nsub * 8 + j][k4 * 4];
            float4 a = acc[j];
            a.x = fmaf(hv.x, w0.x, fmaf(hv.y, w1.x, fmaf(hv.z, w2.x, fmaf(hv.w, w3.x, a.x))));
            a.y = fmaf(hv.x, w0.y, fmaf(hv.y, w1.y, fmaf(hv.z, w2.y, fmaf(hv.w, w3.y, a.y))));
            a.z = fmaf(hv.x, w0.z, fmaf(hv.y, w1.z, fmaf(hv.z, w2.z, fmaf(hv.w, w3.z, a.z))));
            a.w = fmaf(hv.x, w0.w, fmaf(hv.y, w1.w, fmaf(hv.z, w2.w, fmaf(hv.w, w3.w, a.w))));
            acc[j] = a;
        }
    }
#pragma unroll
    for (int j = 0; j < 8; ++j) {
        int n = n0 + nsub * 8 + j;
        if (n < N) {
            h16x4 o;
            o.x = __float2half(acc[j].x);
            o.y = __float2half(acc[j].y);
            o.z = __float2half(acc[j].z);
            o.w = __float2half(acc[j].w);
            *(h16x4*)(xh + (size_t)n * 256 + co4) = o;
        }
    }
    {
        int row  = t >> 3;
        int head = (t >> 1) & 3;
        int sd   = t & 1;
        int n = n0 + row;
        if (n < N) {
            const float* u = uv_l + sd * 256 + head * 64;
            float a = 0.f;
#pragma unroll
            for (int k4 = 0; k4 < 16; ++k4) {
                float4 hv = *(const float4*)&hs[row][k4 * 4];
                float4 uu = *(const float4*)(u + k4 * 4);
                a += hv.x * uu.x + hv.y * uu.y + hv.z * uu.z + hv.w * uu.w;
            }
            (sd ? ad_ : as_)[n * 4 + head] = a;
        }
    }
}

__device__ __forceinline__ __half2 shxor_h2(__half2 a, int m) {
    int u = __shfl_xor(*(int*)&a, m, 64);
    return *(__half2*)&u;
}

// TWO nodes per wave (32 lanes/node): 16 lanes/edge, 2 edge-slots/node.
// All reduce masks (16; 4,8; 1,2) stay within each 32-lane half, so every
// prologue/epilogue wave-instruction serves 2 nodes — per-node fixed cost
// halves (the audited dominant term). Implicit self-loop in slot 0.
// LAST: out-projection, 32 lanes per node (64 active).
template <bool LAST>
__global__ __launch_bounds__(256) void k_gat(
        const __half* __restrict__ xh, const float* __restrict__ as_,
        const float* __restrict__ ad_, const int* __restrict__ cnt,
        const int* __restrict__ csrB, const float* __restrict__ convb,
        const float* __restrict__ ln_g, const float* __restrict__ ln_b,
        float* __restrict__ h, const float* __restrict__ owT,
        const float* __restrict__ out_b, float* __restrict__ out, int N) {
    __shared__ float owT_lds[LAST ? 2048 : 1];
    __shared__ float hout_lds4[4][2][LAST ? 64 : 1];
    __shared__ float hout_nl[4][2][LAST ? 1 : 1];  // placeholder (unused)
    int t = threadIdx.x;
    int wid = t >> 6, lane = t & 63;
    if (LAST) {
        for (int i = t; i < 2048; i += 256) owT_lds[i] = owT[i];
        __syncthreads();
    }
    int ns   = lane >> 5;        // node sub (0/1)
    int l32  = lane & 31;
    int g    = l32 >> 4;         // edge slot 0..1
    int l16  = l32 & 15;
    int head = l16 >> 2;
    int n = blockIdx.x * 8 + wid * 2 + ns;
    if (n < N) {
        int r0 = n << 6;
        int r1 = r0 + 1 + min(cnt[n], 63);
        float adv = ad_[(size_t)n * 4 + head];
        const char* xbb = (const char*)xh + (l16 << 5);
        const char* asb = (const char*)as_ + (head << 2);
        const char* cbb = (const char*)csrB;

        float s = 0.f;
        __half2 acc[8];
#pragma unroll
        for (int j = 0; j < 8; ++j) acc[j] = __float2half2_rn(0.f);

        uint4 zero4 = make_uint4(0u, 0u, 0u, 0u);
        int idx;
        idx = r0 + g;     bool vA = idx < r1; int sA = n; if (g != 0 && vA) sA = *(const int*)(cbb + ((unsigned)idx << 2));
        idx = r0 + 2 + g; bool vB = idx < r1; int sB = 0; if (vB) sB = *(const int*)(cbb + ((unsigned)idx << 2));
        idx = r0 + 4 + g; bool vC = idx < r1; int sC = 0; if (vC) sC = *(const int*)(cbb + ((unsigned)idx << 2));
        idx = r0 + 6 + g; bool vD = idx < r1; int sD = 0; if (vD) sD = *(const int*)(cbb + ((unsigned)idx << 2));
        float asA = 0.f, asB = 0.f;
        uint4 qA0 = zero4, qA1 = zero4, qB0 = zero4, qB1 = zero4;
        if (vA) {
            asA = *(const float*)(asb + ((unsigned)sA << 4));
            const uint4* bp = (const uint4*)(xbb + ((unsigned)sA << 9));
            qA0 = bp[0]; qA1 = bp[1];
        }
        if (vB) {
            asB = *(const float*)(asb + ((unsigned)sB << 4));
            const uint4* bp = (const uint4*)(xbb + ((unsigned)sB << 9));
            qB0 = bp[0]; qB1 = bp[1];
        }

        auto COMPUTE = [&](bool vc, float asc, const uint4& q0, const uint4& q1) {
            float e = asc + adv;
            e = e > 0.f ? e : NEG_SLOPE * e;
            float w = __expf(e);
            w = vc ? w : 0.f;
            s += w;
            __half2 w2 = __float2half2_rn(w);
            const __half2* ha = (const __half2*)&q0;
            const __half2* hb = (const __half2*)&q1;
            acc[0] = __hfma2(w2, ha[0], acc[0]);
            acc[1] = __hfma2(w2, ha[1], acc[1]);
            acc[2] = __hfma2(w2, ha[2], acc[2]);
            acc[3] = __hfma2(w2, ha[3], acc[3]);
            acc[4] = __hfma2(w2, hb[0], acc[4]);
            acc[5] = __hfma2(w2, hb[1], acc[5]);
            acc[6] = __hfma2(w2, hb[2], acc[6]);
            acc[7] = __hfma2(w2, hb[3], acc[7]);
        };

        for (int i = r0; i < r1; i += 4) {
            COMPUTE(vA, asA, qA0, qA1);
            int idxE = i + 8 + g; bool vE = idxE < r1; int sE = 0;
            if (vE) sE = *(const int*)(cbb + ((unsigned)idxE << 2));
            vA = vC;
            if (vC) {
                asA = *(const float*)(asb + ((unsigned)sC << 4));
                const uint4* bp = (const uint4*)(xbb + ((unsigned)sC << 9));
                qA0 = bp[0]; qA1 = bp[1];
            }
            COMPUTE(vB, asB, qB0, qB1);
            int idxF = i + 10 + g; bool vF = idxF < r1; int sF = 0;
            if (vF) sF = *(const int*)(cbb + ((unsigned)idxF << 2));
            vB = vD;
            if (vD) {
                asB = *(const float*)(asb + ((unsigned)sD << 4));
                const uint4* bp = (const uint4*)(xbb + ((unsigned)sD << 9));
                qB0 = bp[0]; qB1 = bp[1];
            }
            vC = vE; sC = sE;
            vD = vF; sD = sF;
        }

        // reduce over the 2 edge-slots (lane bit 4) — within each 32-lane node
        s += __shfl_xor(s, 16, 64);
#pragma unroll
        for (int j = 0; j < 8; ++j)
            acc[j] = __hadd2(acc[j], shxor_h2(acc[j], 16));
        float inv = 1.f / (s + 1e-16f);
        __half2 ih = __float2half2_rn(inv);
#pragma unroll
        for (int j = 0; j < 8; ++j) {
            acc[j] = __hmul2(acc[j], ih);
            acc[j] = __hadd2(acc[j], shxor_h2(acc[j], 4));
            acc[j] = __hadd2(acc[j], shxor_h2(acc[j], 8));
        }
        float f[16];
#pragma unroll
        for (int j = 0; j < 8; ++j) {
            float2 tv = __half22float2(acc[j]);
            f[2 * j]     = tv.x;
            f[2 * j + 1] = tv.y;
        }
        int cblk = l32 & 3;
        int cb16 = cblk * 16;
        float o[16];
        float part = 0.f;
#pragma unroll
        for (int q = 0; q < 4; ++q) {
            float4 cb = *(const float4*)(convb + cb16 + q * 4);
            o[q * 4 + 0] = 0.25f * f[q * 4 + 0] + cb.x;
            o[q * 4 + 1] = 0.25f * f[q * 4 + 1] + cb.y;
            o[q * 4 + 2] = 0.25f * f[q * 4 + 2] + cb.z;
            o[q * 4 + 3] = 0.25f * f[q * 4 + 3] + cb.w;
            part += o[q * 4 + 0] + o[q * 4 + 1] + o[q * 4 + 2] + o[q * 4 + 3];
        }
        part += __shfl_xor(part, 1, 64);
        part += __shfl_xor(part, 2, 64);
        float mu = part * (1.f / 64.f);
        float vs = 0.f;
#pragma unroll
        for (int j = 0; j < 16; ++j) { o[j] -= mu; vs += o[j] * o[j]; }
        vs += __shfl_xor(vs, 1, 64);
        vs += __shfl_xor(vs, 2, 64);
        float rstd = rsqrtf(vs * (1.f / 64.f) + LN_EPS);

        if (!LAST) {
            if (l32 < 4) {
                float4* hp = (float4*)(h + (size_t)n * 64 + cb16);
#pragma unroll
                for (int q = 0; q < 4; ++q) {
                    float4 hv = hp[q];
                    float4 gv = *(const float4*)(ln_g + cb16 + q * 4);
                    float4 bv = *(const float4*)(ln_b + cb16 + q * 4);
                    hv.x += fmaxf(o[q * 4 + 0] * rstd * gv.x + bv.x, 0.f);
                    hv.y += fmaxf(o[q * 4 + 1] * rstd * gv.y + bv.y, 0.f);
                    hv.z += fmaxf(o[q * 4 + 2] * rstd * gv.z + bv.z, 0.f);
                    hv.w += fmaxf(o[q * 4 + 3] * rstd * gv.w + bv.w, 0.f);
                    hp[q] = hv;
                }
            }
        } else {
            float* hout_lds = hout_lds4[wid][ns];
            if (l32 < 4) {
                const float4* hp = (const float4*)(h + (size_t)n * 64 + cb16);
#pragma unroll
                for (int q = 0; q < 4; ++q) {
                    float4 hv = hp[q];
                    float4 gv = *(const float4*)(ln_g + cb16 + q * 4);
                    float4 bv = *(const float4*)(ln_b + cb16 + q * 4);
                    hout_lds[cb16 + q * 4 + 0] = hv.x + fmaxf(o[q * 4 + 0] * rstd * gv.x + bv.x, 0.f);
                    hout_lds[cb16 + q * 4 + 1] = hv.y + fmaxf(o[q * 4 + 1] * rstd * gv.y + bv.y, 0.f);
                    hout_lds[cb16 + q * 4 + 2] = hv.z + fmaxf(o[q * 4 + 2] * rstd * gv.z + bv.z, 0.f);
                    hout_lds[cb16 + q * 4 + 3] = hv.w + fmaxf(o[q * 4 + 3] * rstd * gv.w + bv.w, 0.f);
                }
            }
            asm volatile("s_waitcnt lgkmcnt(0)" ::: "memory");
            float acc2 = out_b[l32];
#pragma unroll 8
            for (int k = 0; k < 64; ++k)
                acc2 = fmaf(hout_lds[k], owT_lds[k * 32 + l32], acc2);
            out[(size_t)n * 32 + l32] = acc2;
        }
    }
}

static inline unsigned cdiv(long long a, long long b) { return (unsigned)((a + b - 1) / b); }

extern "C" void kernel_launch(void* const* d_in, const int* in_sizes, int n_in,
                              void* d_out, int out_size, void* d_ws, size_t ws_size,
                              hipStream_t stream) {
    const float* x          = (const float*)d_in[0];
    const float* drone_feat = (const float*)d_in[1];
    const int*   edge_index = (const int*)d_in[2];
    const int*   batch      = (const int*)d_in[3];
    const float* node_W     = (const float*)d_in[4];
    const float* node_b     = (const float*)d_in[5];
    const float* drone_W    = (const float*)d_in[6];
    const float* drone_b    = (const float*)d_in[7];
    const float* convW[2]   = {(const float*)d_in[8],  (const float*)d_in[14]};
    const float* att_src[2] = {(const float*)d_in[9],  (const float*)d_in[15]};
    const float* att_dst[2] = {(const float*)d_in[10], (const float*)d_in[16]};
    const float* convb[2]   = {(const float*)d_in[11], (const float*)d_in[17]};
    const float* ln_g[2]    = {(const float*)d_in[12], (const float*)d_in[18]};
    const float* ln_b[2]    = {(const float*)d_in[13], (const float*)d_in[19]};
    const float* out_W      = (const float*)d_in[20];
    const float* out_b      = (const float*)d_in[21];
    float* out = (float*)d_out;

    const int N = in_sizes[0] / 32;
    const int E = in_sizes[2] / 2;
    const int P = 4;                        // scatter passes
    const int S = cdiv(N, P);               // dst range per pass
    const int NS = cdiv(cdiv(E, 4), 256);   // scatter blocks per pass
    const int NXH = cdiv(N, 32);            // xh-role blocks (placed FIRST)

    char* base = (char*)d_ws;
    size_t off = 0;
    auto alloc = [&](size_t bytes) {
        char* p = base + off;
        off = (off + bytes + 255) & ~(size_t)255;
        return p;
    };
    float*           h      = (float*)alloc((size_t)N * 64 * 4);
    __half*          xh     = (__half*)alloc((size_t)N * 256 * 2);
    float*           as_    = (float*)alloc((size_t)N * 4 * 4);
    float*           ad_    = (float*)alloc((size_t)N * 4 * 4);
    float*           wt0    = (float*)alloc((size_t)256 * 64 * 4);
    float*           wt1    = (float*)alloc((size_t)256 * 64 * 4);
    float*           uv     = (float*)alloc((size_t)1024 * 4);
    float*           owT    = (float*)alloc((size_t)2048 * 4);
    int*             cnt    = (int*)alloc((size_t)N * 4);
    int*             csrB   = (int*)alloc((size_t)N * 64 * 4);
    (void)ws_size;

    // D1: cnt=0 + layer-0 weight prep (wt0, uv0)
    k_init<<<cdiv(N, 256), 256, 0, stream>>>(convW[0], att_src[0], att_dst[0],
                                             wt0, uv, cnt, N);
    // D2: merged {layer-0 xh (h0 fused), FIRST} || {4-pass windowed scatter + prep}
    k_sx<<<NXH + NS * P, 256, 0, stream>>>(
        edge_index, cnt, csrB,
        convW[1], att_src[1], att_dst[1], out_W,
        wt1, uv, owT, E, S, NS, NXH,
        wt0, xh, as_, ad_,
        x, batch, node_W, drone_W, node_b, drone_b, drone_feat, h, N);
    // D3-D5: gat0, xh1, gat1 (final gat fuses the output projection)
    k_gat<false><<<cdiv(N, 8), 256, 0, stream>>>(xh, as_, ad_, cnt, csrB, convb[0],
                                                 ln_g[0], ln_b[0], h, owT, out_b, out, N);
    k_xh1<<<cdiv(N, 32), 256, 0, stream>>>(h, wt1, uv + 512, xh, as_, ad_, N);
    k_gat<true><<<cdiv(N, 8), 256, 0, stream>>>(xh, as_, ad_, cnt, csrB, convb[1],
                                                ln_g[1], ln_b[1], h, owT, out_b, out, N);
}